// Round 7
// baseline (125.550 us; speedup 1.0000x reference)
//
#include <hip/hip_runtime.h>
#include <hip/hip_bf16.h>

namespace {
constexpr int Bb = 8, Hh = 56, Ww = 56, Cc = 192;
constexpr int NQ  = Hh * Ww;        // 3136
constexpr int NKV = 28 * 28;        // 784
constexpr float EPS = 1e-5f;
constexpr float QSCALE = 0.125f * 1.4426950408889634f;  // head scale * log2(e)
}

typedef __attribute__((ext_vector_type(8))) short          bf16x8;
typedef __attribute__((ext_vector_type(4))) float          f32x4;
typedef __attribute__((ext_vector_type(8))) unsigned short u16x8;

__device__ inline unsigned short f2b(float f) {
  __hip_bfloat16 h = __float2bfloat16(f);     // RNE, hardware cvt path
  return __builtin_bit_cast(unsigned short, h);
}

__device__ inline uint2 pack4(float a, float b, float c, float d) {
  uint2 r;
  r.x = (unsigned)f2b(a) | ((unsigned)f2b(b) << 16);
  r.y = (unsigned)f2b(c) | ((unsigned)f2b(d) << 16);
  return r;
}

// ---------------------------------------------------------------------------
// weight prep: fp32 [K][N] -> bf16 transposed [N][K]  (must precede GEMMs)
// ---------------------------------------------------------------------------
__global__ __launch_bounds__(256) void prep_w_kernel(
    const float* __restrict__ pwq, const float* __restrict__ pwkv,
    const float* __restrict__ outw,
    unsigned short* __restrict__ wq, unsigned short* __restrict__ wkv,
    unsigned short* __restrict__ wo)
{
  int i = blockIdx.x * 256 + threadIdx.x;
  if (i < 36864) {                       // wq [192][192]
    int n = i / 192, k = i - n * 192;
    wq[i] = f2b(pwq[k * 192 + n]);
  } else if (i < 110592) {               // wkv [384][192]
    int j = i - 36864;
    int n = j / 192, k = j - n * 192;
    wkv[j] = f2b(pwkv[k * 384 + n]);
  } else if (i < 147456) {               // wo [192][192]
    int j = i - 110592;
    int n = j / 192, k = j - n * 192;
    wo[j] = f2b(outw[k * 192 + n]);
  }
}

// ---------------------------------------------------------------------------
// fused depthwise-conv+BN + bf16 MFMA GEMM.
//  blocks [0,392):   Q path.  64 A-rows (of 25088) x Wq[192,192]^T -> Qbuf
//  blocks [392,588): KV path. lb=blk-392; bn=lb/98 (0=K half, 1=V half),
//                    64 A-rows (of 6272) x Wkv[bn*192..][192]^T -> Kbuf/Vtbuf
// Phase 1: each block computes dwconv+BN for its 64 rows into As (bf16, LDS).
// Phase 2: K=192 MFMA loop, full-width N=192 (A never re-read), Bs per-chunk.
// 4 waves (2Mx2N): wave-tile 32x96, acc[2][6].
// ---------------------------------------------------------------------------
__global__ __launch_bounds__(256) void dwgemm_kernel(
    const float* __restrict__ x,
    const float* __restrict__ dw_q, const float* __restrict__ q_gamma,
    const float* __restrict__ q_beta, const float* __restrict__ q_mean,
    const float* __restrict__ q_var,
    const float* __restrict__ dw_kv, const float* __restrict__ kv_gamma,
    const float* __restrict__ kv_beta, const float* __restrict__ kv_mean,
    const float* __restrict__ kv_var,
    const unsigned short* __restrict__ Wq, const unsigned short* __restrict__ Wkv,
    unsigned short* __restrict__ Qbuf, unsigned short* __restrict__ Kbuf,
    unsigned short* __restrict__ Vtbuf)
{
  __shared__ unsigned short As[64][200];   // [row][k], pad -> 2-way banks
  __shared__ unsigned short Bs[192][72];   // [n][k-chunk]

  const int blk = blockIdx.x;
  const bool isQ = blk < 392;
  const int lb = isQ ? blk : blk - 392;
  const int bn = isQ ? 0 : lb / 98;        // KV: 0 = K cols, 1 = V cols
  const int row0 = (isQ ? lb : (lb % 98)) * 64;

  const float* dww = isQ ? dw_q : dw_kv;
  const float* gmp = isQ ? q_gamma : kv_gamma;
  const float* btp = isQ ? q_beta  : kv_beta;
  const float* mnp = isQ ? q_mean  : kv_mean;
  const float* vrp = isQ ? q_var   : kv_var;
  const unsigned short* Btw = isQ ? Wq : (Wkv + (size_t)bn * 192 * 192);
  const int OH = isQ ? 56 : 28, OW = isQ ? 56 : 28;
  const int stride = isQ ? 1 : 2, pad = isQ ? 1 : 0;
  const int NR = isQ ? 3136 : 784;

  const int tid = threadIdx.x;

  // ---- phase 1: dwconv + BN -> As (64 rows x 192 ch, bf16) ----
#pragma unroll
  for (int it = 0; it < 12; ++it) {
    const int task = it * 256 + tid;       // 64*48 = 3072 = 12*256
    const int c4 = task % 48, r = task / 48;
    const int p = row0 + r;
    const int b = p / NR;
    const int rem = p - b * NR;
    const int oh = rem / OW, ow = rem - oh * OW;
    const int c = c4 * 4;

    float4 acc = make_float4(0.f, 0.f, 0.f, 0.f);
#pragma unroll
    for (int kh = 0; kh < 3; ++kh) {
      const int ih = oh * stride - pad + kh;
      if (ih < 0 || ih >= Hh) continue;
#pragma unroll
      for (int kw = 0; kw < 3; ++kw) {
        const int iw = ow * stride - pad + kw;
        if (iw < 0 || iw >= Ww) continue;
        float4 xv = *(const float4*)&x[((size_t)(b * Hh + ih) * Ww + iw) * Cc + c];
        float4 wv = *(const float4*)&dww[(kh * 3 + kw) * Cc + c];
        acc.x += xv.x * wv.x; acc.y += xv.y * wv.y;
        acc.z += xv.z * wv.z; acc.w += xv.w * wv.w;
      }
    }
    float4 gm = *(const float4*)&gmp[c];
    float4 bt = *(const float4*)&btp[c];
    float4 mn = *(const float4*)&mnp[c];
    float4 vr = *(const float4*)&vrp[c];
    float r0 = (acc.x - mn.x) * gm.x / sqrtf(vr.x + EPS) + bt.x;
    float r1 = (acc.y - mn.y) * gm.y / sqrtf(vr.y + EPS) + bt.y;
    float r2 = (acc.z - mn.z) * gm.z / sqrtf(vr.z + EPS) + bt.z;
    float r3 = (acc.w - mn.w) * gm.w / sqrtf(vr.w + EPS) + bt.w;
    *reinterpret_cast<uint2*>(&As[r][c]) = pack4(r0, r1, r2, r3);
  }

  // ---- phase 2: MFMA GEMM, C[64,192] = As x Btw^T ----
  const int lane = tid & 63, w = tid >> 6;
  const int lr = lane & 15, lg = lane >> 4;
  const int wm = w >> 1, wn = w & 1;

  f32x4 acc[2][6];
#pragma unroll
  for (int mr = 0; mr < 2; ++mr)
#pragma unroll
    for (int nr = 0; nr < 6; ++nr) acc[mr][nr] = (f32x4){0.f, 0.f, 0.f, 0.f};

  for (int k0 = 0; k0 < 192; k0 += 64) {
    __syncthreads();                       // As ready / prev Bs reads done
    // stage Bs chunk: 192 rows x 64 shorts (1536 u16x8 tasks, 6/thread)
#pragma unroll
    for (int it = 0; it < 6; ++it) {
      const int task = it * 256 + tid;
      const int n = task >> 3, c8 = task & 7;
      *(u16x8*)&Bs[n][c8 * 8] = *(const u16x8*)&Btw[(size_t)n * 192 + k0 + c8 * 8];
    }
    __syncthreads();
#pragma unroll
    for (int ks = 0; ks < 2; ++ks) {
      bf16x8 a[2], b[6];
#pragma unroll
      for (int mr = 0; mr < 2; ++mr)
        a[mr] = *(const bf16x8*)&As[wm * 32 + mr * 16 + lr][k0 + ks * 32 + lg * 8];
#pragma unroll
      for (int nr = 0; nr < 6; ++nr)
        b[nr] = *(const bf16x8*)&Bs[wn * 96 + nr * 16 + lr][ks * 32 + lg * 8];
#pragma unroll
      for (int mr = 0; mr < 2; ++mr)
#pragma unroll
        for (int nr = 0; nr < 6; ++nr)
          acc[mr][nr] = __builtin_amdgcn_mfma_f32_16x16x32_bf16(a[mr], b[nr], acc[mr][nr], 0, 0, 0);
    }
  }

  // ---- epilogue ----
#pragma unroll
  for (int mr = 0; mr < 2; ++mr) {
#pragma unroll
    for (int nr = 0; nr < 6; ++nr) {
      const int c = wn * 96 + nr * 16 + lr;          // 0..191
      const int rbase = row0 + wm * 32 + mr * 16 + lg * 4;
      const int h = c >> 6, d = c & 63;
      const int b = rbase / NR;                       // NR%4==0: 4-row group one b
      const int n0r = rbase - b * NR;
      if (isQ) {
#pragma unroll
        for (int j = 0; j < 4; ++j)
          Qbuf[(((size_t)b * 3 + h) * 3136 + n0r + j) * 64 + d] = f2b(acc[mr][nr][j] * QSCALE);
      } else if (bn == 0) {
#pragma unroll
        for (int j = 0; j < 4; ++j)
          Kbuf[(((size_t)b * 3 + h) * 784 + n0r + j) * 64 + d] = f2b(acc[mr][nr][j]);
      } else {
        uint2 v = pack4(acc[mr][nr][0], acc[mr][nr][1], acc[mr][nr][2], acc[mr][nr][3]);
        *reinterpret_cast<uint2*>(&Vtbuf[(((size_t)b * 3 + h) * 64 + d) * 784 + n0r]) = v;
      }
    }
  }
}

// ---------------------------------------------------------------------------
// output projection: O[25088,192](bf16) x Wo^T + bias -> fp32
// ---------------------------------------------------------------------------
__global__ __launch_bounds__(256) void gemm_out_kernel(
    const unsigned short* __restrict__ A, const unsigned short* __restrict__ Bt,
    const float* __restrict__ bias, float* __restrict__ O32)
{
  __shared__ unsigned short As[128][72];
  __shared__ unsigned short Bs[64][72];

  const int bm = blockIdx.x / 3, bn = blockIdx.x % 3;
  const int row0 = bm << 7, col0 = bn << 6;
  const int tid = threadIdx.x;
  const int lane = tid & 63, w = tid >> 6;
  const int lr = lane & 15, lg = lane >> 4;
  const int wm = w >> 1, wn = w & 1;

  f32x4 acc[4][2];
#pragma unroll
  for (int mr = 0; mr < 4; ++mr)
#pragma unroll
    for (int nr = 0; nr < 2; ++nr) acc[mr][nr] = (f32x4){0.f, 0.f, 0.f, 0.f};

  for (int k0 = 0; k0 < 192; k0 += 64) {
    {
      const int r = tid >> 1, c0 = (tid & 1) * 32;
      const unsigned short* src = A + (size_t)(row0 + r) * 192 + k0 + c0;
#pragma unroll
      for (int u = 0; u < 4; ++u)
        *(u16x8*)&As[r][c0 + u * 8] = *(const u16x8*)&src[u * 8];
    }
    {
      const int n = tid >> 2, c0 = (tid & 3) * 16;
      const unsigned short* src = Bt + (size_t)(col0 + n) * 192 + k0 + c0;
#pragma unroll
      for (int u = 0; u < 2; ++u)
        *(u16x8*)&Bs[n][c0 + u * 8] = *(const u16x8*)&src[u * 8];
    }
    __syncthreads();
#pragma unroll
    for (int ks = 0; ks < 2; ++ks) {
      bf16x8 a[4], b[2];
#pragma unroll
      for (int mr = 0; mr < 4; ++mr)
        a[mr] = *(const bf16x8*)&As[wm * 64 + mr * 16 + lr][ks * 32 + lg * 8];
#pragma unroll
      for (int nr = 0; nr < 2; ++nr)
        b[nr] = *(const bf16x8*)&Bs[wn * 32 + nr * 16 + lr][ks * 32 + lg * 8];
#pragma unroll
      for (int mr = 0; mr < 4; ++mr)
#pragma unroll
        for (int nr = 0; nr < 2; ++nr)
          acc[mr][nr] = __builtin_amdgcn_mfma_f32_16x16x32_bf16(a[mr], b[nr], acc[mr][nr], 0, 0, 0);
    }
    __syncthreads();
  }

#pragma unroll
  for (int mr = 0; mr < 4; ++mr) {
#pragma unroll
    for (int nr = 0; nr < 2; ++nr) {
      const int c = col0 + wn * 32 + nr * 16 + lr;
      const int rbase = row0 + wm * 64 + mr * 16 + lg * 4;
      const float bb = bias[c];
#pragma unroll
      for (int j = 0; j < 4; ++j)
        O32[(size_t)(rbase + j) * 192 + c] = acc[mr][nr][j] + bb;
    }
  }
}

// ---------------------------------------------------------------------------
// MFMA flash attention (unchanged from round 6 — proven).
// ---------------------------------------------------------------------------
__global__ __launch_bounds__(256) void attn_mfma_kernel(
    const unsigned short* __restrict__ Qb, const unsigned short* __restrict__ Kb,
    const unsigned short* __restrict__ Vtb, unsigned short* __restrict__ Ob)
{
  __shared__ unsigned short Ks[64][72];
  __shared__ unsigned short Vts[64][72];   // V transposed tile: [d][kv_local]
  __shared__ unsigned short Ps[64][72];    // P tile (wave-private rows), 72-pad
  __shared__ float ls[4][16];

  const int blk = blockIdx.x;
  const int qt = blk % 49;
  const int bh = blk / 49;                 // b*3 + h
  const int n0 = qt * 64;
  const int tid = threadIdx.x;
  const int lane = tid & 63;
  const int w = tid >> 6;
  const int lr = lane & 15, lg = lane >> 4;
  const int srow = w * 16 + lr;            // staging row
  const int scc  = lg;                     // staging chunk

  const unsigned short* qrow = Qb + ((size_t)bh * NQ + n0 + w * 16 + lr) * 64;
  const bf16x8 aq0 = *(const bf16x8*)&qrow[lg * 8];
  const bf16x8 aq1 = *(const bf16x8*)&qrow[32 + lg * 8];

  const unsigned short* kbase = Kb + (size_t)bh * NKV * 64;
  const unsigned short* vrow  = Vtb + ((size_t)bh * 64 + srow) * NKV;

  u16x8 kr0, kr1, vr0, vr1;
  {
    const unsigned short* kp = kbase + (size_t)srow * 64;
    kr0 = *(const u16x8*)&kp[scc * 8];
    kr1 = *(const u16x8*)&kp[scc * 8 + 32];
    vr0 = *(const u16x8*)&vrow[scc * 8];
    vr1 = *(const u16x8*)&vrow[scc * 8 + 32];
  }
  *(u16x8*)&Ks[srow][scc * 8]       = kr0;
  *(u16x8*)&Ks[srow][scc * 8 + 32]  = kr1;
  *(u16x8*)&Vts[srow][scc * 8]      = vr0;
  *(u16x8*)&Vts[srow][scc * 8 + 32] = vr1;
  __syncthreads();

  f32x4 oacc[4];
#pragma unroll
  for (int db = 0; db < 4; ++db) oacc[db] = (f32x4){0.f, 0.f, 0.f, 0.f};
  float lsum = 0.f;

  for (int kt = 0; kt < 12; ++kt) {
    {
      const int nk = kt + 1;
      const int kvg = (nk * 64 + srow < NKV) ? nk * 64 + srow : NKV - 1;
      const unsigned short* kp = kbase + (size_t)kvg * 64;
      kr0 = *(const u16x8*)&kp[scc * 8];
      kr1 = *(const u16x8*)&kp[scc * 8 + 32];
      const int vb = nk * 64 + scc * 8;
      const int vc0 = (vb      <= NKV - 8) ? vb      : NKV - 8;
      const int vc1 = (vb + 32 <= NKV - 8) ? vb + 32 : NKV - 8;
      vr0 = *(const u16x8*)&vrow[vc0];
      vr1 = *(const u16x8*)&vrow[vc1];
    }

    f32x4 st[4];
#pragma unroll
    for (int nb = 0; nb < 4; ++nb) {
      const bf16x8 bk0 = *(const bf16x8*)&Ks[nb * 16 + lr][lg * 8];
      const bf16x8 bk1 = *(const bf16x8*)&Ks[nb * 16 + lr][32 + lg * 8];
      f32x4 a = (f32x4){0.f, 0.f, 0.f, 0.f};
      a = __builtin_amdgcn_mfma_f32_16x16x32_bf16(bk0, aq0, a, 0, 0, 0);
      a = __builtin_amdgcn_mfma_f32_16x16x32_bf16(bk1, aq1, a, 0, 0, 0);
      st[nb] = a;
    }

#pragma unroll
    for (int nb = 0; nb < 4; ++nb) {
      float p[4];
#pragma unroll
      for (int r = 0; r < 4; ++r) p[r] = exp2f(st[nb][r]);
      lsum += (p[0] + p[1]) + (p[2] + p[3]);
      uint2 u = pack4(p[0], p[1], p[2], p[3]);
      *reinterpret_cast<uint2*>(&Ps[w * 16 + lr][nb * 16 + lg * 4]) = u;
    }

    const bf16x8 pa0 = *(const bf16x8*)&Ps[w * 16 + lr][lg * 8];
    const bf16x8 pa1 = *(const bf16x8*)&Ps[w * 16 + lr][32 + lg * 8];
#pragma unroll
    for (int db = 0; db < 4; ++db) {
      const bf16x8 vb0 = *(const bf16x8*)&Vts[db * 16 + lr][lg * 8];
      const bf16x8 vb1 = *(const bf16x8*)&Vts[db * 16 + lr][32 + lg * 8];
      oacc[db] = __builtin_amdgcn_mfma_f32_16x16x32_bf16(pa0, vb0, oacc[db], 0, 0, 0);
      oacc[db] = __builtin_amdgcn_mfma_f32_16x16x32_bf16(pa1, vb1, oacc[db], 0, 0, 0);
    }

    __syncthreads();
    *(u16x8*)&Ks[srow][scc * 8]       = kr0;
    *(u16x8*)&Ks[srow][scc * 8 + 32]  = kr1;
    *(u16x8*)&Vts[srow][scc * 8]      = vr0;
    *(u16x8*)&Vts[srow][scc * 8 + 32] = vr1;
    __syncthreads();
  }

  // tail tile (kt=12): kv 768..783 valid -> only nb=0
  {
    const bf16x8 bk0 = *(const bf16x8*)&Ks[lr][lg * 8];
    const bf16x8 bk1 = *(const bf16x8*)&Ks[lr][32 + lg * 8];
    f32x4 a = (f32x4){0.f, 0.f, 0.f, 0.f};
    a = __builtin_amdgcn_mfma_f32_16x16x32_bf16(bk0, aq0, a, 0, 0, 0);
    a = __builtin_amdgcn_mfma_f32_16x16x32_bf16(bk1, aq1, a, 0, 0, 0);
    float p[4];
#pragma unroll
    for (int r = 0; r < 4; ++r) p[r] = exp2f(a[r]);
    lsum += (p[0] + p[1]) + (p[2] + p[3]);
    *reinterpret_cast<uint2*>(&Ps[w * 16 + lr][lg * 4]) = pack4(p[0], p[1], p[2], p[3]);
    uint2 z; z.x = 0u; z.y = 0u;
    *reinterpret_cast<uint2*>(&Ps[w * 16 + lr][16 + lg * 4]) = z;
    const bf16x8 pa0 = *(const bf16x8*)&Ps[w * 16 + lr][lg * 8];
#pragma unroll
    for (int db = 0; db < 4; ++db) {
      const bf16x8 vb0 = *(const bf16x8*)&Vts[db * 16 + lr][lg * 8];
      oacc[db] = __builtin_amdgcn_mfma_f32_16x16x32_bf16(pa0, vb0, oacc[db], 0, 0, 0);
    }
  }

  float l = lsum;
  l += __shfl_xor(l, 16);
  l += __shfl_xor(l, 32);
  if (lg == 0) ls[w][lr] = l;
  const float4 lv = *(const float4*)&ls[w][lg * 4];

  const int b = bh / 3, h = bh - b * 3;
  float linv[4];
#pragma unroll
  for (int j = 0; j < 4; ++j) linv[j] = 1.f / ((&lv.x)[j]);
#pragma unroll
  for (int j = 0; j < 4; ++j) {
    const int qg = n0 + w * 16 + lg * 4 + j;
    unsigned short* orow = Ob + ((size_t)b * NQ + qg) * 192 + h * 64 + lr;
#pragma unroll
    for (int db = 0; db < 4; ++db) orow[db * 16] = f2b(oacc[db][j] * linv[j]);
  }
}

// ---------------------------------------------------------------------------
extern "C" void kernel_launch(void* const* d_in, const int* in_sizes, int n_in,
                              void* d_out, int out_size, void* d_ws, size_t ws_size,
                              hipStream_t stream)
{
  const float* x        = (const float*)d_in[0];
  const float* dw_q     = (const float*)d_in[1];
  const float* q_gamma  = (const float*)d_in[2];
  const float* q_beta   = (const float*)d_in[3];
  const float* q_mean   = (const float*)d_in[4];
  const float* q_var    = (const float*)d_in[5];
  const float* pw_q     = (const float*)d_in[6];
  const float* dw_kv    = (const float*)d_in[7];
  const float* kv_gamma = (const float*)d_in[8];
  const float* kv_beta  = (const float*)d_in[9];
  const float* kv_mean  = (const float*)d_in[10];
  const float* kv_var   = (const float*)d_in[11];
  const float* pw_kv    = (const float*)d_in[12];
  const float* out_w    = (const float*)d_in[13];
  const float* out_b    = (const float*)d_in[14];
  float* out = (float*)d_out;

  unsigned short* Obuf  = (unsigned short*)d_ws;          // 25088*192
  unsigned short* Qbuf  = Obuf  + (size_t)25088 * 192;    // 24*3136*64
  unsigned short* Kbuf  = Qbuf  + (size_t)24 * 3136 * 64; // 24*784*64
  unsigned short* Vtbuf = Kbuf  + (size_t)24 * 784 * 64;  // 24*64*784
  unsigned short* Wq    = Vtbuf + (size_t)24 * 784 * 64;  // 192*192
  unsigned short* Wkv   = Wq + 36864;                     // 384*192
  unsigned short* Wo    = Wkv + 73728;                    // 192*192

  // 1. weight transpose -> bf16 (must precede GEMM consumers)
  prep_w_kernel<<<576, 256, 0, stream>>>(pw_q, pw_kv, out_w, Wq, Wkv, Wo);
  // 2. fused dwconv+BN + pointwise GEMMs -> Qbuf (scaled) / Kbuf / Vtbuf
  dwgemm_kernel<<<588, 256, 0, stream>>>(
      x, dw_q, q_gamma, q_beta, q_mean, q_var,
      dw_kv, kv_gamma, kv_beta, kv_mean, kv_var,
      Wq, Wkv, Qbuf, Kbuf, Vtbuf);
  // 3. MFMA attention -> Obuf (bf16 O, [25088][192])
  attn_mfma_kernel<<<8 * 3 * 49, 256, 0, stream>>>(Qbuf, Kbuf, Vtbuf, Obuf);
  // 4. output projection + bias -> d_out (fp32)
  gemm_out_kernel<<<588, 256, 0, stream>>>(Obuf, Wo, out_b, out);
}

// Round 8
// 93.118 us; speedup vs baseline: 1.3483x; 1.3483x over previous
//
#include <hip/hip_runtime.h>
#include <hip/hip_bf16.h>

namespace {
constexpr int Bb = 8, Hh = 56, Ww = 56, Cc = 192;
constexpr int NQ  = Hh * Ww;        // 3136
constexpr int NKV = 28 * 28;        // 784
constexpr float EPS = 1e-5f;
constexpr float QSCALE = 0.125f * 1.4426950408889634f;  // head scale * log2(e)
}

typedef __attribute__((ext_vector_type(8))) short          bf16x8;
typedef __attribute__((ext_vector_type(4))) float          f32x4;
typedef __attribute__((ext_vector_type(8))) unsigned short u16x8;

__device__ inline unsigned short f2b(float f) {
  __hip_bfloat16 h = __float2bfloat16(f);     // RNE, hardware cvt path
  return __builtin_bit_cast(unsigned short, h);
}

__device__ inline uint2 pack4(float a, float b, float c, float d) {
  uint2 r;
  r.x = (unsigned)f2b(a) | ((unsigned)f2b(b) << 16);
  r.y = (unsigned)f2b(c) | ((unsigned)f2b(d) << 16);
  return r;
}

// ---------------------------------------------------------------------------
// depthwise 3x3 conv (SAME) + batchnorm body (4 channels / thread)
// ---------------------------------------------------------------------------
__device__ inline void dwbn_body(
    int idx, const float* __restrict__ x, const float* __restrict__ w,
    const float* __restrict__ gamma, const float* __restrict__ beta,
    const float* __restrict__ mean, const float* __restrict__ var,
    unsigned short* __restrict__ out, int OH, int OW, int stride, int pad)
{
  int c4 = idx % 48;
  int t = idx / 48;
  int ow = t % OW; t /= OW;
  int oh = t % OH; int b = t / OH;
  const int c = c4 * 4;

  float4 acc = make_float4(0.f, 0.f, 0.f, 0.f);
#pragma unroll
  for (int kh = 0; kh < 3; ++kh) {
    int ih = oh * stride - pad + kh;
    if (ih < 0 || ih >= Hh) continue;
#pragma unroll
    for (int kw = 0; kw < 3; ++kw) {
      int iw = ow * stride - pad + kw;
      if (iw < 0 || iw >= Ww) continue;
      float4 xv = *(const float4*)&x[((size_t)(b * Hh + ih) * Ww + iw) * Cc + c];
      float4 wv = *(const float4*)&w[(kh * 3 + kw) * Cc + c];
      acc.x += xv.x * wv.x; acc.y += xv.y * wv.y;
      acc.z += xv.z * wv.z; acc.w += xv.w * wv.w;
    }
  }
  float4 gm = *(const float4*)&gamma[c];
  float4 bt = *(const float4*)&beta[c];
  float4 mn = *(const float4*)&mean[c];
  float4 vr = *(const float4*)&var[c];
  float r0 = (acc.x - mn.x) * gm.x / sqrtf(vr.x + EPS) + bt.x;
  float r1 = (acc.y - mn.y) * gm.y / sqrtf(vr.y + EPS) + bt.y;
  float r2 = (acc.z - mn.z) * gm.z / sqrtf(vr.z + EPS) + bt.z;
  float r3 = (acc.w - mn.w) * gm.w / sqrtf(vr.w + EPS) + bt.w;
  const size_t row = (size_t)(b * OH + oh) * OW + ow;
  *reinterpret_cast<uint2*>(&out[row * 192 + c]) = pack4(r0, r1, r2, r3);
}

// ---------------------------------------------------------------------------
// fused stage 1: dwbn(q) [blocks 0..4703] + dwbn(kv) [4704..5879]
//              + weight transpose->bf16 [5880..6455]
// ---------------------------------------------------------------------------
__global__ __launch_bounds__(256) void stage1_kernel(
    const float* __restrict__ x,
    const float* __restrict__ dw_q, const float* __restrict__ q_gamma,
    const float* __restrict__ q_beta, const float* __restrict__ q_mean,
    const float* __restrict__ q_var,
    const float* __restrict__ dw_kv, const float* __restrict__ kv_gamma,
    const float* __restrict__ kv_beta, const float* __restrict__ kv_mean,
    const float* __restrict__ kv_var,
    const float* __restrict__ pwq, const float* __restrict__ pwkv,
    const float* __restrict__ outw,
    unsigned short* __restrict__ dwq, unsigned short* __restrict__ dwkv,
    unsigned short* __restrict__ wq, unsigned short* __restrict__ wkv,
    unsigned short* __restrict__ wo)
{
  const int blk = blockIdx.x;
  if (blk < 4704) {
    dwbn_body(blk * 256 + threadIdx.x, x, dw_q, q_gamma, q_beta, q_mean, q_var,
              dwq, 56, 56, 1, 1);
  } else if (blk < 5880) {
    dwbn_body((blk - 4704) * 256 + threadIdx.x, x, dw_kv, kv_gamma, kv_beta,
              kv_mean, kv_var, dwkv, 28, 28, 2, 0);
  } else {
    int i = (blk - 5880) * 256 + threadIdx.x;
    if (i < 36864) {                       // wq [192][192]
      int n = i / 192, k = i - n * 192;
      wq[i] = f2b(pwq[k * 192 + n]);
    } else if (i < 110592) {               // wkv [384][192]
      int j = i - 36864;
      int n = j / 192, k = j - n * 192;
      wkv[j] = f2b(pwkv[k * 384 + n]);
    } else {                               // wo [192][192]
      int j = i - 110592;
      int n = j / 192, k = j - n * 192;
      wo[j] = f2b(outw[k * 192 + n]);
    }
  }
}

// ---------------------------------------------------------------------------
// full-N bf16 MFMA GEMM for q & kv pointwise (A read ONCE per 64-row block):
//  blocks [0,392):   Q: rows blk*64 of dwq x Wq^T (N=192) -> Qbuf (scaled)
//  blocks [392,588): KV: lb=blk-392; half=lb/98 (0=K,1=V); rows (lb%98)*64 of
//                    dwkv x Wkv[half*192..][192]^T (N=192) -> Kbuf / Vtbuf
// 4 waves (2Mx2N): wave-tile 32x96, acc[2][6]. K-order (k0,ks) identical to
// round-6 -> bitwise-identical outputs.
// ---------------------------------------------------------------------------
__global__ __launch_bounds__(256) void gemm_qkv_kernel(
    const unsigned short* __restrict__ dwq, const unsigned short* __restrict__ dwkv,
    const unsigned short* __restrict__ Wq, const unsigned short* __restrict__ Wkv,
    unsigned short* __restrict__ Qbuf, unsigned short* __restrict__ Kbuf,
    unsigned short* __restrict__ Vtbuf)
{
  __shared__ unsigned short As[64][72];
  __shared__ unsigned short Bs[192][72];

  const int blk = blockIdx.x;
  const bool isQ = blk < 392;
  const int lb = isQ ? blk : blk - 392;
  const int half = isQ ? 0 : lb / 98;      // KV: 0 = K cols, 1 = V cols
  const int row0 = (isQ ? lb : (lb % 98)) * 64;
  const unsigned short* __restrict__ A  = isQ ? dwq : dwkv;
  const unsigned short* __restrict__ Bt = isQ ? Wq : (Wkv + (size_t)half * 192 * 192);
  const int NR = isQ ? 3136 : 784;

  const int tid = threadIdx.x;
  const int lane = tid & 63, w = tid >> 6;
  const int lr = lane & 15, lg = lane >> 4;
  const int wm = w >> 1, wn = w & 1;

  f32x4 acc[2][6];
#pragma unroll
  for (int mr = 0; mr < 2; ++mr)
#pragma unroll
    for (int nr = 0; nr < 6; ++nr) acc[mr][nr] = (f32x4){0.f, 0.f, 0.f, 0.f};

  for (int k0 = 0; k0 < 192; k0 += 64) {
    // stage As chunk: 64 rows x 64 shorts = 512 u16x8 tasks (2/thread)
#pragma unroll
    for (int it = 0; it < 2; ++it) {
      const int task = it * 256 + tid;
      const int r = task >> 3, c8 = task & 7;
      *(u16x8*)&As[r][c8 * 8] = *(const u16x8*)&A[(size_t)(row0 + r) * 192 + k0 + c8 * 8];
    }
    // stage Bs chunk: 192 rows x 64 shorts = 1536 tasks (6/thread)
#pragma unroll
    for (int it = 0; it < 6; ++it) {
      const int task = it * 256 + tid;
      const int n = task >> 3, c8 = task & 7;
      *(u16x8*)&Bs[n][c8 * 8] = *(const u16x8*)&Bt[(size_t)n * 192 + k0 + c8 * 8];
    }
    __syncthreads();
#pragma unroll
    for (int ks = 0; ks < 2; ++ks) {
      bf16x8 a[2], b[6];
#pragma unroll
      for (int mr = 0; mr < 2; ++mr)
        a[mr] = *(const bf16x8*)&As[wm * 32 + mr * 16 + lr][ks * 32 + lg * 8];
#pragma unroll
      for (int nr = 0; nr < 6; ++nr)
        b[nr] = *(const bf16x8*)&Bs[wn * 96 + nr * 16 + lr][ks * 32 + lg * 8];
#pragma unroll
      for (int mr = 0; mr < 2; ++mr)
#pragma unroll
        for (int nr = 0; nr < 6; ++nr)
          acc[mr][nr] = __builtin_amdgcn_mfma_f32_16x16x32_bf16(a[mr], b[nr], acc[mr][nr], 0, 0, 0);
    }
    __syncthreads();
  }

#pragma unroll
  for (int mr = 0; mr < 2; ++mr) {
#pragma unroll
    for (int nr = 0; nr < 6; ++nr) {
      const int c = wn * 96 + nr * 16 + lr;           // 0..191
      const int rbase = row0 + wm * 32 + mr * 16 + lg * 4;
      const int h = c >> 6, d = c & 63;
      const int b = rbase / NR;                        // NR%4==0: group one b
      const int n0r = rbase - b * NR;
      if (isQ) {
#pragma unroll
        for (int j = 0; j < 4; ++j)
          Qbuf[(((size_t)b * 3 + h) * 3136 + n0r + j) * 64 + d] = f2b(acc[mr][nr][j] * QSCALE);
      } else if (half == 0) {
#pragma unroll
        for (int j = 0; j < 4; ++j)
          Kbuf[(((size_t)b * 3 + h) * 784 + n0r + j) * 64 + d] = f2b(acc[mr][nr][j]);
      } else {
        uint2 v = pack4(acc[mr][nr][0], acc[mr][nr][1], acc[mr][nr][2], acc[mr][nr][3]);
        *reinterpret_cast<uint2*>(&Vtbuf[(((size_t)b * 3 + h) * 64 + d) * 784 + n0r]) = v;
      }
    }
  }
}

// ---------------------------------------------------------------------------
// output projection, full-N: rows blk*64 of O[25088,192](bf16) x Wo^T + bias
// -> fp32. A read once per block.
// ---------------------------------------------------------------------------
__global__ __launch_bounds__(256) void gemm_out_kernel(
    const unsigned short* __restrict__ A, const unsigned short* __restrict__ Bt,
    const float* __restrict__ bias, float* __restrict__ O32)
{
  __shared__ unsigned short As[64][72];
  __shared__ unsigned short Bs[192][72];

  const int row0 = blockIdx.x * 64;
  const int tid = threadIdx.x;
  const int lane = tid & 63, w = tid >> 6;
  const int lr = lane & 15, lg = lane >> 4;
  const int wm = w >> 1, wn = w & 1;

  f32x4 acc[2][6];
#pragma unroll
  for (int mr = 0; mr < 2; ++mr)
#pragma unroll
    for (int nr = 0; nr < 6; ++nr) acc[mr][nr] = (f32x4){0.f, 0.f, 0.f, 0.f};

  for (int k0 = 0; k0 < 192; k0 += 64) {
#pragma unroll
    for (int it = 0; it < 2; ++it) {
      const int task = it * 256 + tid;
      const int r = task >> 3, c8 = task & 7;
      *(u16x8*)&As[r][c8 * 8] = *(const u16x8*)&A[(size_t)(row0 + r) * 192 + k0 + c8 * 8];
    }
#pragma unroll
    for (int it = 0; it < 6; ++it) {
      const int task = it * 256 + tid;
      const int n = task >> 3, c8 = task & 7;
      *(u16x8*)&Bs[n][c8 * 8] = *(const u16x8*)&Bt[(size_t)n * 192 + k0 + c8 * 8];
    }
    __syncthreads();
#pragma unroll
    for (int ks = 0; ks < 2; ++ks) {
      bf16x8 a[2], b[6];
#pragma unroll
      for (int mr = 0; mr < 2; ++mr)
        a[mr] = *(const bf16x8*)&As[wm * 32 + mr * 16 + lr][ks * 32 + lg * 8];
#pragma unroll
      for (int nr = 0; nr < 6; ++nr)
        b[nr] = *(const bf16x8*)&Bs[wn * 96 + nr * 16 + lr][ks * 32 + lg * 8];
#pragma unroll
      for (int mr = 0; mr < 2; ++mr)
#pragma unroll
        for (int nr = 0; nr < 6; ++nr)
          acc[mr][nr] = __builtin_amdgcn_mfma_f32_16x16x32_bf16(a[mr], b[nr], acc[mr][nr], 0, 0, 0);
    }
    __syncthreads();
  }

#pragma unroll
  for (int mr = 0; mr < 2; ++mr) {
#pragma unroll
    for (int nr = 0; nr < 6; ++nr) {
      const int c = wn * 96 + nr * 16 + lr;
      const int rbase = row0 + wm * 32 + mr * 16 + lg * 4;
      const float bb = bias[c];
#pragma unroll
      for (int j = 0; j < 4; ++j)
        O32[(size_t)(rbase + j) * 192 + c] = acc[mr][nr][j] + bb;
    }
  }
}

// ---------------------------------------------------------------------------
// MFMA flash attention (verbatim round 6 — proven).
// ---------------------------------------------------------------------------
__global__ __launch_bounds__(256) void attn_mfma_kernel(
    const unsigned short* __restrict__ Qb, const unsigned short* __restrict__ Kb,
    const unsigned short* __restrict__ Vtb, unsigned short* __restrict__ Ob)
{
  __shared__ unsigned short Ks[64][72];
  __shared__ unsigned short Vts[64][72];   // V transposed tile: [d][kv_local]
  __shared__ unsigned short Ps[64][72];    // P tile (wave-private rows), 72-pad
  __shared__ float ls[4][16];

  const int blk = blockIdx.x;
  const int qt = blk % 49;
  const int bh = blk / 49;                 // b*3 + h
  const int n0 = qt * 64;
  const int tid = threadIdx.x;
  const int lane = tid & 63;
  const int w = tid >> 6;
  const int lr = lane & 15, lg = lane >> 4;
  const int srow = w * 16 + lr;            // staging row
  const int scc  = lg;                     // staging chunk

  const unsigned short* qrow = Qb + ((size_t)bh * NQ + n0 + w * 16 + lr) * 64;
  const bf16x8 aq0 = *(const bf16x8*)&qrow[lg * 8];
  const bf16x8 aq1 = *(const bf16x8*)&qrow[32 + lg * 8];

  const unsigned short* kbase = Kb + (size_t)bh * NKV * 64;
  const unsigned short* vrow  = Vtb + ((size_t)bh * 64 + srow) * NKV;

  u16x8 kr0, kr1, vr0, vr1;
  {
    const unsigned short* kp = kbase + (size_t)srow * 64;
    kr0 = *(const u16x8*)&kp[scc * 8];
    kr1 = *(const u16x8*)&kp[scc * 8 + 32];
    vr0 = *(const u16x8*)&vrow[scc * 8];
    vr1 = *(const u16x8*)&vrow[scc * 8 + 32];
  }
  *(u16x8*)&Ks[srow][scc * 8]       = kr0;
  *(u16x8*)&Ks[srow][scc * 8 + 32]  = kr1;
  *(u16x8*)&Vts[srow][scc * 8]      = vr0;
  *(u16x8*)&Vts[srow][scc * 8 + 32] = vr1;
  __syncthreads();

  f32x4 oacc[4];
#pragma unroll
  for (int db = 0; db < 4; ++db) oacc[db] = (f32x4){0.f, 0.f, 0.f, 0.f};
  float lsum = 0.f;

  for (int kt = 0; kt < 12; ++kt) {
    {
      const int nk = kt + 1;
      const int kvg = (nk * 64 + srow < NKV) ? nk * 64 + srow : NKV - 1;
      const unsigned short* kp = kbase + (size_t)kvg * 64;
      kr0 = *(const u16x8*)&kp[scc * 8];
      kr1 = *(const u16x8*)&kp[scc * 8 + 32];
      const int vb = nk * 64 + scc * 8;
      const int vc0 = (vb      <= NKV - 8) ? vb      : NKV - 8;
      const int vc1 = (vb + 32 <= NKV - 8) ? vb + 32 : NKV - 8;
      vr0 = *(const u16x8*)&vrow[vc0];
      vr1 = *(const u16x8*)&vrow[vc1];
    }

    f32x4 st[4];
#pragma unroll
    for (int nb = 0; nb < 4; ++nb) {
      const bf16x8 bk0 = *(const bf16x8*)&Ks[nb * 16 + lr][lg * 8];
      const bf16x8 bk1 = *(const bf16x8*)&Ks[nb * 16 + lr][32 + lg * 8];
      f32x4 a = (f32x4){0.f, 0.f, 0.f, 0.f};
      a = __builtin_amdgcn_mfma_f32_16x16x32_bf16(bk0, aq0, a, 0, 0, 0);
      a = __builtin_amdgcn_mfma_f32_16x16x32_bf16(bk1, aq1, a, 0, 0, 0);
      st[nb] = a;
    }

#pragma unroll
    for (int nb = 0; nb < 4; ++nb) {
      float p[4];
#pragma unroll
      for (int r = 0; r < 4; ++r) p[r] = exp2f(st[nb][r]);
      lsum += (p[0] + p[1]) + (p[2] + p[3]);
      uint2 u = pack4(p[0], p[1], p[2], p[3]);
      *reinterpret_cast<uint2*>(&Ps[w * 16 + lr][nb * 16 + lg * 4]) = u;
    }

    const bf16x8 pa0 = *(const bf16x8*)&Ps[w * 16 + lr][lg * 8];
    const bf16x8 pa1 = *(const bf16x8*)&Ps[w * 16 + lr][32 + lg * 8];
#pragma unroll
    for (int db = 0; db < 4; ++db) {
      const bf16x8 vb0 = *(const bf16x8*)&Vts[db * 16 + lr][lg * 8];
      const bf16x8 vb1 = *(const bf16x8*)&Vts[db * 16 + lr][32 + lg * 8];
      oacc[db] = __builtin_amdgcn_mfma_f32_16x16x32_bf16(pa0, vb0, oacc[db], 0, 0, 0);
      oacc[db] = __builtin_amdgcn_mfma_f32_16x16x32_bf16(pa1, vb1, oacc[db], 0, 0, 0);
    }

    __syncthreads();
    *(u16x8*)&Ks[srow][scc * 8]       = kr0;
    *(u16x8*)&Ks[srow][scc * 8 + 32]  = kr1;
    *(u16x8*)&Vts[srow][scc * 8]      = vr0;
    *(u16x8*)&Vts[srow][scc * 8 + 32] = vr1;
    __syncthreads();
  }

  // tail tile (kt=12): kv 768..783 valid -> only nb=0
  {
    const bf16x8 bk0 = *(const bf16x8*)&Ks[lr][lg * 8];
    const bf16x8 bk1 = *(const bf16x8*)&Ks[lr][32 + lg * 8];
    f32x4 a = (f32x4){0.f, 0.f, 0.f, 0.f};
    a = __builtin_amdgcn_mfma_f32_16x16x32_bf16(bk0, aq0, a, 0, 0, 0);
    a = __builtin_amdgcn_mfma_f32_16x16x32_bf16(bk1, aq1, a, 0, 0, 0);
    float p[4];
#pragma unroll
    for (int r = 0; r < 4; ++r) p[r] = exp2f(a[r]);
    lsum += (p[0] + p[1]) + (p[2] + p[3]);
    *reinterpret_cast<uint2*>(&Ps[w * 16 + lr][lg * 4]) = pack4(p[0], p[1], p[2], p[3]);
    uint2 z; z.x = 0u; z.y = 0u;
    *reinterpret_cast<uint2*>(&Ps[w * 16 + lr][16 + lg * 4]) = z;
    const bf16x8 pa0 = *(const bf16x8*)&Ps[w * 16 + lr][lg * 8];
#pragma unroll
    for (int db = 0; db < 4; ++db) {
      const bf16x8 vb0 = *(const bf16x8*)&Vts[db * 16 + lr][lg * 8];
      oacc[db] = __builtin_amdgcn_mfma_f32_16x16x32_bf16(pa0, vb0, oacc[db], 0, 0, 0);
    }
  }

  float l = lsum;
  l += __shfl_xor(l, 16);
  l += __shfl_xor(l, 32);
  if (lg == 0) ls[w][lr] = l;
  const float4 lv = *(const float4*)&ls[w][lg * 4];

  const int b = bh / 3, h = bh - b * 3;
  float linv[4];
#pragma unroll
  for (int j = 0; j < 4; ++j) linv[j] = 1.f / ((&lv.x)[j]);
#pragma unroll
  for (int j = 0; j < 4; ++j) {
    const int qg = n0 + w * 16 + lg * 4 + j;
    unsigned short* orow = Ob + ((size_t)b * NQ + qg) * 192 + h * 64 + lr;
#pragma unroll
    for (int db = 0; db < 4; ++db) orow[db * 16] = f2b(oacc[db][j] * linv[j]);
  }
}

// ---------------------------------------------------------------------------
extern "C" void kernel_launch(void* const* d_in, const int* in_sizes, int n_in,
                              void* d_out, int out_size, void* d_ws, size_t ws_size,
                              hipStream_t stream)
{
  const float* x        = (const float*)d_in[0];
  const float* dw_q     = (const float*)d_in[1];
  const float* q_gamma  = (const float*)d_in[2];
  const float* q_beta   = (const float*)d_in[3];
  const float* q_mean   = (const float*)d_in[4];
  const float* q_var    = (const float*)d_in[5];
  const float* pw_q     = (const float*)d_in[6];
  const float* dw_kv    = (const float*)d_in[7];
  const float* kv_gamma = (const float*)d_in[8];
  const float* kv_beta  = (const float*)d_in[9];
  const float* kv_mean  = (const float*)d_in[10];
  const float* kv_var   = (const float*)d_in[11];
  const float* pw_kv    = (const float*)d_in[12];
  const float* out_w    = (const float*)d_in[13];
  const float* out_b    = (const float*)d_in[14];
  float* out = (float*)d_out;

  unsigned short* dwq   = (unsigned short*)d_ws;          // 25088*192 (later O)
  unsigned short* dwkv  = dwq   + (size_t)25088 * 192;    // 6272*192
  unsigned short* Qbuf  = dwkv  + (size_t)6272 * 192;     // 24*3136*64
  unsigned short* Kbuf  = Qbuf  + (size_t)24 * 3136 * 64; // 24*784*64
  unsigned short* Vtbuf = Kbuf  + (size_t)24 * 784 * 64;  // 24*64*784
  unsigned short* Wq    = Vtbuf + (size_t)24 * 784 * 64;  // 192*192
  unsigned short* Wkv   = Wq + 36864;                     // 384*192
  unsigned short* Wo    = Wkv + 73728;                    // 192*192

  // 1. fused: dwbn(q) + dwbn(kv) + weight prep
  stage1_kernel<<<6456, 256, 0, stream>>>(
      x, dw_q, q_gamma, q_beta, q_mean, q_var,
      dw_kv, kv_gamma, kv_beta, kv_mean, kv_var,
      pw_q, pw_kv, out_w, dwq, dwkv, Wq, Wkv, Wo);
  // 2. full-N pointwise GEMMs: q -> Qbuf (scaled), kv -> Kbuf + Vtbuf
  gemm_qkv_kernel<<<588, 256, 0, stream>>>(dwq, dwkv, Wq, Wkv, Qbuf, Kbuf, Vtbuf);
  // 3. MFMA attention -> dwq (bf16 O, [25088][192]; dwq dead after step 2)
  attn_mfma_kernel<<<8 * 3 * 49, 256, 0, stream>>>(Qbuf, Kbuf, Vtbuf, dwq);
  // 4. output projection + bias -> d_out (fp32), full-N
  gemm_out_kernel<<<392, 256, 0, stream>>>(dwq, Wo, out_b, out);
}

// Round 10
// 91.447 us; speedup vs baseline: 1.3729x; 1.0183x over previous
//
#include <hip/hip_runtime.h>
#include <hip/hip_bf16.h>

namespace {
constexpr int Bb = 8, Hh = 56, Ww = 56, Cc = 192;
constexpr int NQ  = Hh * Ww;        // 3136
constexpr int NKV = 28 * 28;        // 784
constexpr float EPS = 1e-5f;
constexpr float QSCALE = 0.125f * 1.4426950408889634f;  // head scale * log2(e)
}

typedef __attribute__((ext_vector_type(8))) short          bf16x8;
typedef __attribute__((ext_vector_type(4))) float          f32x4;
typedef __attribute__((ext_vector_type(8))) unsigned short u16x8;

__device__ inline unsigned short f2b(float f) {
  __hip_bfloat16 h = __float2bfloat16(f);     // RNE, hardware cvt path
  return __builtin_bit_cast(unsigned short, h);
}

__device__ inline uint2 pack4(float a, float b, float c, float d) {
  uint2 r;
  r.x = (unsigned)f2b(a) | ((unsigned)f2b(b) << 16);
  r.y = (unsigned)f2b(c) | ((unsigned)f2b(d) << 16);
  return r;
}

// ---------------------------------------------------------------------------
// depthwise 3x3 conv (SAME) + batchnorm body (4 channels / thread)
// ---------------------------------------------------------------------------
__device__ inline void dwbn_body(
    int idx, const float* __restrict__ x, const float* __restrict__ w,
    const float* __restrict__ gamma, const float* __restrict__ beta,
    const float* __restrict__ mean, const float* __restrict__ var,
    unsigned short* __restrict__ out, int OH, int OW, int stride, int pad)
{
  int c4 = idx % 48;
  int t = idx / 48;
  int ow = t % OW; t /= OW;
  int oh = t % OH; int b = t / OH;
  const int c = c4 * 4;

  float4 acc = make_float4(0.f, 0.f, 0.f, 0.f);
#pragma unroll
  for (int kh = 0; kh < 3; ++kh) {
    int ih = oh * stride - pad + kh;
    if (ih < 0 || ih >= Hh) continue;
#pragma unroll
    for (int kw = 0; kw < 3; ++kw) {
      int iw = ow * stride - pad + kw;
      if (iw < 0 || iw >= Ww) continue;
      float4 xv = *(const float4*)&x[((size_t)(b * Hh + ih) * Ww + iw) * Cc + c];
      float4 wv = *(const float4*)&w[(kh * 3 + kw) * Cc + c];
      acc.x += xv.x * wv.x; acc.y += xv.y * wv.y;
      acc.z += xv.z * wv.z; acc.w += xv.w * wv.w;
    }
  }
  float4 gm = *(const float4*)&gamma[c];
  float4 bt = *(const float4*)&beta[c];
  float4 mn = *(const float4*)&mean[c];
  float4 vr = *(const float4*)&var[c];
  float r0 = (acc.x - mn.x) * gm.x / sqrtf(vr.x + EPS) + bt.x;
  float r1 = (acc.y - mn.y) * gm.y / sqrtf(vr.y + EPS) + bt.y;
  float r2 = (acc.z - mn.z) * gm.z / sqrtf(vr.z + EPS) + bt.z;
  float r3 = (acc.w - mn.w) * gm.w / sqrtf(vr.w + EPS) + bt.w;
  const size_t row = (size_t)(b * OH + oh) * OW + ow;
  *reinterpret_cast<uint2*>(&out[row * 192 + c]) = pack4(r0, r1, r2, r3);
}

// ---------------------------------------------------------------------------
// fused stage 1: dwbn(q) [blocks 0..4703] + dwbn(kv) [4704..5879]
//              + weight transpose->bf16 [5880..6455]
// ---------------------------------------------------------------------------
__global__ __launch_bounds__(256) void stage1_kernel(
    const float* __restrict__ x,
    const float* __restrict__ dw_q, const float* __restrict__ q_gamma,
    const float* __restrict__ q_beta, const float* __restrict__ q_mean,
    const float* __restrict__ q_var,
    const float* __restrict__ dw_kv, const float* __restrict__ kv_gamma,
    const float* __restrict__ kv_beta, const float* __restrict__ kv_mean,
    const float* __restrict__ kv_var,
    const float* __restrict__ pwq, const float* __restrict__ pwkv,
    const float* __restrict__ outw,
    unsigned short* __restrict__ dwq, unsigned short* __restrict__ dwkv,
    unsigned short* __restrict__ wq, unsigned short* __restrict__ wkv,
    unsigned short* __restrict__ wo)
{
  const int blk = blockIdx.x;
  if (blk < 4704) {
    dwbn_body(blk * 256 + threadIdx.x, x, dw_q, q_gamma, q_beta, q_mean, q_var,
              dwq, 56, 56, 1, 1);
  } else if (blk < 5880) {
    dwbn_body((blk - 4704) * 256 + threadIdx.x, x, dw_kv, kv_gamma, kv_beta,
              kv_mean, kv_var, dwkv, 28, 28, 2, 0);
  } else {
    int i = (blk - 5880) * 256 + threadIdx.x;
    if (i < 36864) {                       // wq [192][192]
      int n = i / 192, k = i - n * 192;
      wq[i] = f2b(pwq[k * 192 + n]);
    } else if (i < 110592) {               // wkv [384][192]
      int j = i - 36864;
      int n = j / 192, k = j - n * 192;
      wkv[j] = f2b(pwkv[k * 384 + n]);
    } else {                               // wo [192][192]
      int j = i - 110592;
      int n = j / 192, k = j - n * 192;
      wo[j] = f2b(outw[k * 192 + n]);
    }
  }
}

// ---------------------------------------------------------------------------
// bf16 MFMA GEMM for q & kv pointwise (round-6 proven 128x64 tiling):
//  blocks [0,588): dwq[25088,192] x Wq^T -> Qbuf (per-head, scaled by QSCALE)
//  blocks [588,882): dwkv[6272,192] x Wkv^T -> Kbuf (per-head) + Vtbuf
// ---------------------------------------------------------------------------
__global__ __launch_bounds__(256) void gemm_qkv_kernel(
    const unsigned short* __restrict__ dwq, const unsigned short* __restrict__ dwkv,
    const unsigned short* __restrict__ Wq, const unsigned short* __restrict__ Wkv,
    unsigned short* __restrict__ Qbuf, unsigned short* __restrict__ Kbuf,
    unsigned short* __restrict__ Vtbuf)
{
  __shared__ unsigned short As[128][72];
  __shared__ unsigned short Bs[64][72];

  const int blk = blockIdx.x;
  const bool isQ = blk < 588;
  const int lb = isQ ? blk : blk - 588;
  const unsigned short* __restrict__ A  = isQ ? dwq : dwkv;
  const unsigned short* __restrict__ Bt = isQ ? Wq : Wkv;
  const int nbl = isQ ? 3 : 6;
  const int NR  = isQ ? 3136 : 784;

  const int bm = lb / nbl, bn = lb % nbl;
  const int row0 = bm << 7, col0 = bn << 6;
  const int tid = threadIdx.x;
  const int lane = tid & 63, w = tid >> 6;
  const int lr = lane & 15, lg = lane >> 4;
  const int wm = w >> 1, wn = w & 1;

  f32x4 acc[4][2];
#pragma unroll
  for (int mr = 0; mr < 4; ++mr)
#pragma unroll
    for (int nr = 0; nr < 2; ++nr) acc[mr][nr] = (f32x4){0.f, 0.f, 0.f, 0.f};

  for (int k0 = 0; k0 < 192; k0 += 64) {
    {
      const int r = tid >> 1, c0 = (tid & 1) * 32;
      const unsigned short* src = A + (size_t)(row0 + r) * 192 + k0 + c0;
#pragma unroll
      for (int u = 0; u < 4; ++u)
        *(u16x8*)&As[r][c0 + u * 8] = *(const u16x8*)&src[u * 8];
    }
    {
      const int n = tid >> 2, c0 = (tid & 3) * 16;
      const unsigned short* src = Bt + (size_t)(col0 + n) * 192 + k0 + c0;  // col0 restored (round-9 bug)
#pragma unroll
      for (int u = 0; u < 2; ++u)
        *(u16x8*)&Bs[n][c0 + u * 8] = *(const u16x8*)&src[u * 8];
    }
    __syncthreads();
#pragma unroll
    for (int ks = 0; ks < 2; ++ks) {
      bf16x8 a[4], b[2];
#pragma unroll
      for (int mr = 0; mr < 4; ++mr)
        a[mr] = *(const bf16x8*)&As[wm * 64 + mr * 16 + lr][ks * 32 + lg * 8];
#pragma unroll
      for (int nr = 0; nr < 2; ++nr)
        b[nr] = *(const bf16x8*)&Bs[wn * 32 + nr * 16 + lr][ks * 32 + lg * 8];
#pragma unroll
      for (int mr = 0; mr < 4; ++mr)
#pragma unroll
        for (int nr = 0; nr < 2; ++nr)
          acc[mr][nr] = __builtin_amdgcn_mfma_f32_16x16x32_bf16(a[mr], b[nr], acc[mr][nr], 0, 0, 0);
    }
    __syncthreads();
  }

#pragma unroll
  for (int mr = 0; mr < 4; ++mr) {
#pragma unroll
    for (int nr = 0; nr < 2; ++nr) {
      const int c = col0 + wn * 32 + nr * 16 + lr;
      const int rbase = row0 + wm * 64 + mr * 16 + lg * 4;
      if (isQ) {
        const int h = c >> 6, d = c & 63;
        const int b = rbase / 3136;
        const int n0 = rbase - b * 3136;
#pragma unroll
        for (int j = 0; j < 4; ++j)
          Qbuf[(((size_t)b * 3 + h) * 3136 + n0 + j) * 64 + d] = f2b(acc[mr][nr][j] * QSCALE);
      } else if (c < 192) {
        const int h = c >> 6, d = c & 63;
        const int b = rbase / 784;
        const int n0 = rbase - b * 784;
#pragma unroll
        for (int j = 0; j < 4; ++j)
          Kbuf[(((size_t)b * 3 + h) * 784 + n0 + j) * 64 + d] = f2b(acc[mr][nr][j]);
      } else {
        const int h = (c - 192) >> 6, d = (c - 192) & 63;
        const int b = rbase / 784;
        const int n0 = rbase - b * 784;
        uint2 v = pack4(acc[mr][nr][0], acc[mr][nr][1], acc[mr][nr][2], acc[mr][nr][3]);
        *reinterpret_cast<uint2*>(&Vtbuf[(((size_t)b * 3 + h) * 64 + d) * 784 + n0]) = v;
      }
    }
  }
}

// ---------------------------------------------------------------------------
// output projection (round-6 proven): O[25088,192](bf16) x Wo^T + bias -> fp32
// ---------------------------------------------------------------------------
__global__ __launch_bounds__(256) void gemm_out_kernel(
    const unsigned short* __restrict__ A, const unsigned short* __restrict__ Bt,
    const float* __restrict__ bias, float* __restrict__ O32)
{
  __shared__ unsigned short As[128][72];
  __shared__ unsigned short Bs[64][72];

  const int bm = blockIdx.x / 3, bn = blockIdx.x % 3;
  const int row0 = bm << 7, col0 = bn << 6;
  const int tid = threadIdx.x;
  const int lane = tid & 63, w = tid >> 6;
  const int lr = lane & 15, lg = lane >> 4;
  const int wm = w >> 1, wn = w & 1;

  f32x4 acc[4][2];
#pragma unroll
  for (int mr = 0; mr < 4; ++mr)
#pragma unroll
    for (int nr = 0; nr < 2; ++nr) acc[mr][nr] = (f32x4){0.f, 0.f, 0.f, 0.f};

  for (int k0 = 0; k0 < 192; k0 += 64) {
    {
      const int r = tid >> 1, c0 = (tid & 1) * 32;
      const unsigned short* src = A + (size_t)(row0 + r) * 192 + k0 + c0;
#pragma unroll
      for (int u = 0; u < 4; ++u)
        *(u16x8*)&As[r][c0 + u * 8] = *(const u16x8*)&src[u * 8];
    }
    {
      const int n = tid >> 2, c0 = (tid & 3) * 16;
      const unsigned short* src = Bt + (size_t)(col0 + n) * 192 + k0 + c0;
#pragma unroll
      for (int u = 0; u < 2; ++u)
        *(u16x8*)&Bs[n][c0 + u * 8] = *(const u16x8*)&src[u * 8];
    }
    __syncthreads();
#pragma unroll
    for (int ks = 0; ks < 2; ++ks) {
      bf16x8 a[4], b[2];
#pragma unroll
      for (int mr = 0; mr < 4; ++mr)
        a[mr] = *(const bf16x8*)&As[wm * 64 + mr * 16 + lr][ks * 32 + lg * 8];
#pragma unroll
      for (int nr = 0; nr < 2; ++nr)
        b[nr] = *(const bf16x8*)&Bs[wn * 32 + nr * 16 + lr][ks * 32 + lg * 8];
#pragma unroll
      for (int mr = 0; mr < 4; ++mr)
#pragma unroll
        for (int nr = 0; nr < 2; ++nr)
          acc[mr][nr] = __builtin_amdgcn_mfma_f32_16x16x32_bf16(a[mr], b[nr], acc[mr][nr], 0, 0, 0);
    }
    __syncthreads();
  }

#pragma unroll
  for (int mr = 0; mr < 4; ++mr) {
#pragma unroll
    for (int nr = 0; nr < 2; ++nr) {
      const int c = col0 + wn * 32 + nr * 16 + lr;
      const int rbase = row0 + wm * 64 + mr * 16 + lg * 4;
      const float bb = bias[c];
#pragma unroll
      for (int j = 0; j < 4; ++j)
        O32[(size_t)(rbase + j) * 192 + c] = acc[mr][nr][j] + bb;
    }
  }
}

// ---------------------------------------------------------------------------
// MFMA flash attention, 32 q-rows per wave (halved K/V fragment-read
// redundancy). Block = (bh, 128 q-rows), grid 24*25; last qt has 64 valid
// rows (clamped Q reads, predicated stores). Per valid row the op sequence
// is identical to round 6 -> bitwise-identical output.
// ---------------------------------------------------------------------------
__global__ __launch_bounds__(256) void attn_mfma_kernel(
    const unsigned short* __restrict__ Qb, const unsigned short* __restrict__ Kb,
    const unsigned short* __restrict__ Vtb, unsigned short* __restrict__ Ob)
{
  __shared__ unsigned short Ks[64][72];
  __shared__ unsigned short Vts[64][72];   // V transposed tile: [d][kv_local]
  __shared__ unsigned short Ps[128][72];   // P tile (wave-private rows)
  __shared__ float ls[4][2][16];

  const int blk = blockIdx.x;
  const int qt = blk % 25;
  const int bh = blk / 25;                 // b*3 + h
  const int n0 = qt * 128;
  const int tid = threadIdx.x;
  const int lane = tid & 63;
  const int w = tid >> 6;
  const int lr = lane & 15, lg = lane >> 4;
  const int srow = w * 16 + lr;            // staging row (0..63)
  const int scc  = lg;                     // staging chunk

  // Q fragments: set A = rows w*32+[0,16), set B = +16 (clamped at tail)
  const int qrA = n0 + w * 32 + lr;
  const int qrB = qrA + 16;
  const unsigned short* qpA = Qb + ((size_t)bh * NQ + (qrA < NQ ? qrA : NQ - 1)) * 64;
  const unsigned short* qpB = Qb + ((size_t)bh * NQ + (qrB < NQ ? qrB : NQ - 1)) * 64;
  const bf16x8 qa0 = *(const bf16x8*)&qpA[lg * 8];
  const bf16x8 qa1 = *(const bf16x8*)&qpA[32 + lg * 8];
  const bf16x8 qb0 = *(const bf16x8*)&qpB[lg * 8];
  const bf16x8 qb1 = *(const bf16x8*)&qpB[32 + lg * 8];

  const unsigned short* kbase = Kb + (size_t)bh * NKV * 64;
  const unsigned short* vrow  = Vtb + ((size_t)bh * 64 + srow) * NKV;

  // stage tile 0
  u16x8 kr0, kr1, vr0, vr1;
  {
    const unsigned short* kp = kbase + (size_t)srow * 64;
    kr0 = *(const u16x8*)&kp[scc * 8];
    kr1 = *(const u16x8*)&kp[scc * 8 + 32];
    vr0 = *(const u16x8*)&vrow[scc * 8];
    vr1 = *(const u16x8*)&vrow[scc * 8 + 32];
  }
  *(u16x8*)&Ks[srow][scc * 8]       = kr0;
  *(u16x8*)&Ks[srow][scc * 8 + 32]  = kr1;
  *(u16x8*)&Vts[srow][scc * 8]      = vr0;
  *(u16x8*)&Vts[srow][scc * 8 + 32] = vr1;
  __syncthreads();

  f32x4 oaccA[4], oaccB[4];
#pragma unroll
  for (int db = 0; db < 4; ++db) {
    oaccA[db] = (f32x4){0.f, 0.f, 0.f, 0.f};
    oaccB[db] = (f32x4){0.f, 0.f, 0.f, 0.f};
  }
  float lsumA = 0.f, lsumB = 0.f;

  const int rowA = w * 32 + lr;            // P row, set A
  const int rowB = rowA + 16;              // P row, set B

  for (int kt = 0; kt < 12; ++kt) {
    // prefetch tile kt+1 into regs (latency hides under compute)
    {
      const int nk = kt + 1;
      const int kvg = (nk * 64 + srow < NKV) ? nk * 64 + srow : NKV - 1;
      const unsigned short* kp = kbase + (size_t)kvg * 64;
      kr0 = *(const u16x8*)&kp[scc * 8];
      kr1 = *(const u16x8*)&kp[scc * 8 + 32];
      const int vb = nk * 64 + scc * 8;
      const int vc0 = (vb      <= NKV - 8) ? vb      : NKV - 8;
      const int vc1 = (vb + 32 <= NKV - 8) ? vb + 32 : NKV - 8;
      vr0 = *(const u16x8*)&vrow[vc0];
      vr1 = *(const u16x8*)&vrow[vc1];
    }

    // S^T = K.Q^T for both q-sets: st[nb][r] = S[q][kv = kt*64+nb*16+lg*4+r]
    f32x4 stA[4], stB[4];
#pragma unroll
    for (int nb = 0; nb < 4; ++nb) {
      const bf16x8 bk0 = *(const bf16x8*)&Ks[nb * 16 + lr][lg * 8];
      const bf16x8 bk1 = *(const bf16x8*)&Ks[nb * 16 + lr][32 + lg * 8];
      f32x4 a = (f32x4){0.f, 0.f, 0.f, 0.f};
      a = __builtin_amdgcn_mfma_f32_16x16x32_bf16(bk0, qa0, a, 0, 0, 0);
      a = __builtin_amdgcn_mfma_f32_16x16x32_bf16(bk1, qa1, a, 0, 0, 0);
      stA[nb] = a;
      f32x4 b = (f32x4){0.f, 0.f, 0.f, 0.f};
      b = __builtin_amdgcn_mfma_f32_16x16x32_bf16(bk0, qb0, b, 0, 0, 0);
      b = __builtin_amdgcn_mfma_f32_16x16x32_bf16(bk1, qb1, b, 0, 0, 0);
      stB[nb] = b;
    }

    // p = exp2(s'), partial denominators, pack -> Ps (b64 writes)
#pragma unroll
    for (int nb = 0; nb < 4; ++nb) {
      float pA[4], pB[4];
#pragma unroll
      for (int r = 0; r < 4; ++r) { pA[r] = exp2f(stA[nb][r]); pB[r] = exp2f(stB[nb][r]); }
      lsumA += (pA[0] + pA[1]) + (pA[2] + pA[3]);
      lsumB += (pB[0] + pB[1]) + (pB[2] + pB[3]);
      *reinterpret_cast<uint2*>(&Ps[rowA][nb * 16 + lg * 4]) = pack4(pA[0], pA[1], pA[2], pA[3]);
      *reinterpret_cast<uint2*>(&Ps[rowB][nb * 16 + lg * 4]) = pack4(pB[0], pB[1], pB[2], pB[3]);
    }

    // O += P V  (Ps rows wave-private: same-wave DS in-order, no barrier)
    const bf16x8 paA0 = *(const bf16x8*)&Ps[rowA][lg * 8];
    const bf16x8 paA1 = *(const bf16x8*)&Ps[rowA][32 + lg * 8];
    const bf16x8 paB0 = *(const bf16x8*)&Ps[rowB][lg * 8];
    const bf16x8 paB1 = *(const bf16x8*)&Ps[rowB][32 + lg * 8];
#pragma unroll
    for (int db = 0; db < 4; ++db) {
      const bf16x8 vb0 = *(const bf16x8*)&Vts[db * 16 + lr][lg * 8];
      const bf16x8 vb1 = *(const bf16x8*)&Vts[db * 16 + lr][32 + lg * 8];
      oaccA[db] = __builtin_amdgcn_mfma_f32_16x16x32_bf16(paA0, vb0, oaccA[db], 0, 0, 0);
      oaccA[db] = __builtin_amdgcn_mfma_f32_16x16x32_bf16(paA1, vb1, oaccA[db], 0, 0, 0);
      oaccB[db] = __builtin_amdgcn_mfma_f32_16x16x32_bf16(paB0, vb0, oaccB[db], 0, 0, 0);
      oaccB[db] = __builtin_amdgcn_mfma_f32_16x16x32_bf16(paB1, vb1, oaccB[db], 0, 0, 0);
    }

    // publish prefetched tile kt+1
    __syncthreads();
    *(u16x8*)&Ks[srow][scc * 8]       = kr0;
    *(u16x8*)&Ks[srow][scc * 8 + 32]  = kr1;
    *(u16x8*)&Vts[srow][scc * 8]      = vr0;
    *(u16x8*)&Vts[srow][scc * 8 + 32] = vr1;
    __syncthreads();
  }

  // tail tile (kt=12): kv 768..783 valid -> only nb=0; zero nb=1 slot
  {
    const bf16x8 bk0 = *(const bf16x8*)&Ks[lr][lg * 8];
    const bf16x8 bk1 = *(const bf16x8*)&Ks[lr][32 + lg * 8];
    f32x4 a = (f32x4){0.f, 0.f, 0.f, 0.f};
    a = __builtin_amdgcn_mfma_f32_16x16x32_bf16(bk0, qa0, a, 0, 0, 0);
    a = __builtin_amdgcn_mfma_f32_16x16x32_bf16(bk1, qa1, a, 0, 0, 0);
    f32x4 b = (f32x4){0.f, 0.f, 0.f, 0.f};
    b = __builtin_amdgcn_mfma_f32_16x16x32_bf16(bk0, qb0, b, 0, 0, 0);
    b = __builtin_amdgcn_mfma_f32_16x16x32_bf16(bk1, qb1, b, 0, 0, 0);
    float pA[4], pB[4];
#pragma unroll
    for (int r = 0; r < 4; ++r) { pA[r] = exp2f(a[r]); pB[r] = exp2f(b[r]); }
    lsumA += (pA[0] + pA[1]) + (pA[2] + pA[3]);
    lsumB += (pB[0] + pB[1]) + (pB[2] + pB[3]);
    *reinterpret_cast<uint2*>(&Ps[rowA][lg * 4]) = pack4(pA[0], pA[1], pA[2], pA[3]);
    *reinterpret_cast<uint2*>(&Ps[rowB][lg * 4]) = pack4(pB[0], pB[1], pB[2], pB[3]);
    uint2 z; z.x = 0u; z.y = 0u;
    *reinterpret_cast<uint2*>(&Ps[rowA][16 + lg * 4]) = z;
    *reinterpret_cast<uint2*>(&Ps[rowB][16 + lg * 4]) = z;
    const bf16x8 paA0 = *(const bf16x8*)&Ps[rowA][lg * 8];
    const bf16x8 paB0 = *(const bf16x8*)&Ps[rowB][lg * 8];
#pragma unroll
    for (int db = 0; db < 4; ++db) {
      const bf16x8 vb0 = *(const bf16x8*)&Vts[db * 16 + lr][lg * 8];
      oaccA[db] = __builtin_amdgcn_mfma_f32_16x16x32_bf16(paA0, vb0, oaccA[db], 0, 0, 0);
      oaccB[db] = __builtin_amdgcn_mfma_f32_16x16x32_bf16(paB0, vb0, oaccB[db], 0, 0, 0);
    }
  }

  // final denominators (per set): lanes {lr,+16,+32,+48} hold partials
  float lA = lsumA;
  lA += __shfl_xor(lA, 16);
  lA += __shfl_xor(lA, 32);
  float lB = lsumB;
  lB += __shfl_xor(lB, 16);
  lB += __shfl_xor(lB, 32);
  if (lg == 0) { ls[w][0][lr] = lA; ls[w][1][lr] = lB; }
  const float4 lvA = *(const float4*)&ls[w][0][lg * 4];  // wave-private, in-order
  const float4 lvB = *(const float4*)&ls[w][1][lg * 4];

  const int b = bh / 3, h = bh - b * 3;
#pragma unroll
  for (int j = 0; j < 4; ++j) {
    const int qgA = n0 + w * 32 + lg * 4 + j;     // oaccA row = q (set A)
    if (qgA < NQ) {
      const float inv = 1.f / ((&lvA.x)[j]);
      unsigned short* orow = Ob + ((size_t)b * NQ + qgA) * 192 + h * 64 + lr;
#pragma unroll
      for (int db = 0; db < 4; ++db) orow[db * 16] = f2b(oaccA[db][j] * inv);
    }
    const int qgB = qgA + 16;                     // set B
    if (qgB < NQ) {
      const float inv = 1.f / ((&lvB.x)[j]);
      unsigned short* orow = Ob + ((size_t)b * NQ + qgB) * 192 + h * 64 + lr;
#pragma unroll
      for (int db = 0; db < 4; ++db) orow[db * 16] = f2b(oaccB[db][j] * inv);
    }
  }
}

// ---------------------------------------------------------------------------
extern "C" void kernel_launch(void* const* d_in, const int* in_sizes, int n_in,
                              void* d_out, int out_size, void* d_ws, size_t ws_size,
                              hipStream_t stream)
{
  const float* x        = (const float*)d_in[0];
  const float* dw_q     = (const float*)d_in[1];
  const float* q_gamma  = (const float*)d_in[2];
  const float* q_beta   = (const float*)d_in[3];
  const float* q_mean   = (const float*)d_in[4];
  const float* q_var    = (const float*)d_in[5];
  const float* pw_q     = (const float*)d_in[6];
  const float* dw_kv    = (const float*)d_in[7];
  const float* kv_gamma = (const float*)d_in[8];
  const float* kv_beta  = (const float*)d_in[9];
  const float* kv_mean  = (const float*)d_in[10];
  const float* kv_var   = (const float*)d_in[11];
  const float* pw_kv    = (const float*)d_in[12];
  const float* out_w    = (const float*)d_in[13];
  const float* out_b    = (const float*)d_in[14];
  float* out = (float*)d_out;

  unsigned short* dwq   = (unsigned short*)d_ws;          // 25088*192 (later O)
  unsigned short* dwkv  = dwq   + (size_t)25088 * 192;    // 6272*192
  unsigned short* Qbuf  = dwkv  + (size_t)6272 * 192;     // 24*3136*64
  unsigned short* Kbuf  = Qbuf  + (size_t)24 * 3136 * 64; // 24*784*64
  unsigned short* Vtbuf = Kbuf  + (size_t)24 * 784 * 64;  // 24*64*784
  unsigned short* Wq    = Vtbuf + (size_t)24 * 784 * 64;  // 192*192
  unsigned short* Wkv   = Wq + 36864;                     // 384*192
  unsigned short* Wo    = Wkv + 73728;                    // 192*192

  // 1. fused: dwbn(q) + dwbn(kv) + weight prep
  stage1_kernel<<<6456, 256, 0, stream>>>(
      x, dw_q, q_gamma, q_beta, q_mean, q_var,
      dw_kv, kv_gamma, kv_beta, kv_mean, kv_var,
      pw_q, pw_kv, out_w, dwq, dwkv, Wq, Wkv, Wo);
  // 2. pointwise GEMMs (round-6 tiling): q -> Qbuf, kv -> Kbuf + Vtbuf
  gemm_qkv_kernel<<<882, 256, 0, stream>>>(dwq, dwkv, Wq, Wkv, Qbuf, Kbuf, Vtbuf);
  // 3. MFMA attention (128 q-rows/block) -> dwq (bf16 O)
  attn_mfma_kernel<<<24 * 25, 256, 0, stream>>>(Qbuf, Kbuf, Vtbuf, dwq);
  // 4. output projection + bias -> d_out (fp32)
  gemm_out_kernel<<<588, 256, 0, stream>>>(dwq, Wo, out_b, out);
}

// Round 11
// 91.420 us; speedup vs baseline: 1.3733x; 1.0003x over previous
//
#include <hip/hip_runtime.h>
#include <hip/hip_bf16.h>

namespace {
constexpr int Bb = 8, Hh = 56, Ww = 56, Cc = 192;
constexpr int NQ  = Hh * Ww;        // 3136
constexpr int NKV = 28 * 28;        // 784
constexpr float EPS = 1e-5f;
constexpr float QSCALE = 0.125f * 1.4426950408889634f;  // head scale * log2(e)
}

typedef __attribute__((ext_vector_type(8))) short          bf16x8;
typedef __attribute__((ext_vector_type(4))) float          f32x4;
typedef __attribute__((ext_vector_type(8))) unsigned short u16x8;

__device__ inline unsigned short f2b(float f) {
  __hip_bfloat16 h = __float2bfloat16(f);     // RNE, hardware cvt path
  return __builtin_bit_cast(unsigned short, h);
}

__device__ inline uint2 pack4(float a, float b, float c, float d) {
  uint2 r;
  r.x = (unsigned)f2b(a) | ((unsigned)f2b(b) << 16);
  r.y = (unsigned)f2b(c) | ((unsigned)f2b(d) << 16);
  return r;
}

// ---------------------------------------------------------------------------
// depthwise 3x3 conv (SAME) + batchnorm body (4 channels / thread)
// ---------------------------------------------------------------------------
__device__ inline void dwbn_body(
    int idx, const float* __restrict__ x, const float* __restrict__ w,
    const float* __restrict__ gamma, const float* __restrict__ beta,
    const float* __restrict__ mean, const float* __restrict__ var,
    unsigned short* __restrict__ out, int OH, int OW, int stride, int pad)
{
  int c4 = idx % 48;
  int t = idx / 48;
  int ow = t % OW; t /= OW;
  int oh = t % OH; int b = t / OH;
  const int c = c4 * 4;

  float4 acc = make_float4(0.f, 0.f, 0.f, 0.f);
#pragma unroll
  for (int kh = 0; kh < 3; ++kh) {
    int ih = oh * stride - pad + kh;
    if (ih < 0 || ih >= Hh) continue;
#pragma unroll
    for (int kw = 0; kw < 3; ++kw) {
      int iw = ow * stride - pad + kw;
      if (iw < 0 || iw >= Ww) continue;
      float4 xv = *(const float4*)&x[((size_t)(b * Hh + ih) * Ww + iw) * Cc + c];
      float4 wv = *(const float4*)&w[(kh * 3 + kw) * Cc + c];
      acc.x += xv.x * wv.x; acc.y += xv.y * wv.y;
      acc.z += xv.z * wv.z; acc.w += xv.w * wv.w;
    }
  }
  float4 gm = *(const float4*)&gamma[c];
  float4 bt = *(const float4*)&beta[c];
  float4 mn = *(const float4*)&mean[c];
  float4 vr = *(const float4*)&var[c];
  float r0 = (acc.x - mn.x) * gm.x / sqrtf(vr.x + EPS) + bt.x;
  float r1 = (acc.y - mn.y) * gm.y / sqrtf(vr.y + EPS) + bt.y;
  float r2 = (acc.z - mn.z) * gm.z / sqrtf(vr.z + EPS) + bt.z;
  float r3 = (acc.w - mn.w) * gm.w / sqrtf(vr.w + EPS) + bt.w;
  const size_t row = (size_t)(b * OH + oh) * OW + ow;
  *reinterpret_cast<uint2*>(&out[row * 192 + c]) = pack4(r0, r1, r2, r3);
}

// ---------------------------------------------------------------------------
// fused stage 1: dwbn(q) [blocks 0..4703] + dwbn(kv) [4704..5879]
//              + weight transpose->bf16 [5880..6455]
// ---------------------------------------------------------------------------
__global__ __launch_bounds__(256) void stage1_kernel(
    const float* __restrict__ x,
    const float* __restrict__ dw_q, const float* __restrict__ q_gamma,
    const float* __restrict__ q_beta, const float* __restrict__ q_mean,
    const float* __restrict__ q_var,
    const float* __restrict__ dw_kv, const float* __restrict__ kv_gamma,
    const float* __restrict__ kv_beta, const float* __restrict__ kv_mean,
    const float* __restrict__ kv_var,
    const float* __restrict__ pwq, const float* __restrict__ pwkv,
    const float* __restrict__ outw,
    unsigned short* __restrict__ dwq, unsigned short* __restrict__ dwkv,
    unsigned short* __restrict__ wq, unsigned short* __restrict__ wkv,
    unsigned short* __restrict__ wo)
{
  const int blk = blockIdx.x;
  if (blk < 4704) {
    dwbn_body(blk * 256 + threadIdx.x, x, dw_q, q_gamma, q_beta, q_mean, q_var,
              dwq, 56, 56, 1, 1);
  } else if (blk < 5880) {
    dwbn_body((blk - 4704) * 256 + threadIdx.x, x, dw_kv, kv_gamma, kv_beta,
              kv_mean, kv_var, dwkv, 28, 28, 2, 0);
  } else {
    int i = (blk - 5880) * 256 + threadIdx.x;
    if (i < 36864) {                       // wq [192][192]
      int n = i / 192, k = i - n * 192;
      wq[i] = f2b(pwq[k * 192 + n]);
    } else if (i < 110592) {               // wkv [384][192]
      int j = i - 36864;
      int n = j / 192, k = j - n * 192;
      wkv[j] = f2b(pwkv[k * 384 + n]);
    } else {                               // wo [192][192]
      int j = i - 110592;
      int n = j / 192, k = j - n * 192;
      wo[j] = f2b(outw[k * 192 + n]);
    }
  }
}

// ---------------------------------------------------------------------------
// bf16 MFMA GEMM for q & kv pointwise (round-6 proven 128x64 tiling):
//  blocks [0,588): dwq[25088,192] x Wq^T -> Qbuf (per-head, scaled by QSCALE)
//  blocks [588,882): dwkv[6272,192] x Wkv^T -> Kbuf (per-head) + Vtbuf
// ---------------------------------------------------------------------------
__global__ __launch_bounds__(256) void gemm_qkv_kernel(
    const unsigned short* __restrict__ dwq, const unsigned short* __restrict__ dwkv,
    const unsigned short* __restrict__ Wq, const unsigned short* __restrict__ Wkv,
    unsigned short* __restrict__ Qbuf, unsigned short* __restrict__ Kbuf,
    unsigned short* __restrict__ Vtbuf)
{
  __shared__ unsigned short As[128][72];
  __shared__ unsigned short Bs[64][72];

  const int blk = blockIdx.x;
  const bool isQ = blk < 588;
  const int lb = isQ ? blk : blk - 588;
  const unsigned short* __restrict__ A  = isQ ? dwq : dwkv;
  const unsigned short* __restrict__ Bt = isQ ? Wq : Wkv;
  const int nbl = isQ ? 3 : 6;
  const int NR  = isQ ? 3136 : 784;

  const int bm = lb / nbl, bn = lb % nbl;
  const int row0 = bm << 7, col0 = bn << 6;
  const int tid = threadIdx.x;
  const int lane = tid & 63, w = tid >> 6;
  const int lr = lane & 15, lg = lane >> 4;
  const int wm = w >> 1, wn = w & 1;

  f32x4 acc[4][2];
#pragma unroll
  for (int mr = 0; mr < 4; ++mr)
#pragma unroll
    for (int nr = 0; nr < 2; ++nr) acc[mr][nr] = (f32x4){0.f, 0.f, 0.f, 0.f};

  for (int k0 = 0; k0 < 192; k0 += 64) {
    {
      const int r = tid >> 1, c0 = (tid & 1) * 32;
      const unsigned short* src = A + (size_t)(row0 + r) * 192 + k0 + c0;
#pragma unroll
      for (int u = 0; u < 4; ++u)
        *(u16x8*)&As[r][c0 + u * 8] = *(const u16x8*)&src[u * 8];
    }
    {
      const int n = tid >> 2, c0 = (tid & 3) * 16;
      const unsigned short* src = Bt + (size_t)(col0 + n) * 192 + k0 + c0;
#pragma unroll
      for (int u = 0; u < 2; ++u)
        *(u16x8*)&Bs[n][c0 + u * 8] = *(const u16x8*)&src[u * 8];
    }
    __syncthreads();
#pragma unroll
    for (int ks = 0; ks < 2; ++ks) {
      bf16x8 a[4], b[2];
#pragma unroll
      for (int mr = 0; mr < 4; ++mr)
        a[mr] = *(const bf16x8*)&As[wm * 64 + mr * 16 + lr][ks * 32 + lg * 8];
#pragma unroll
      for (int nr = 0; nr < 2; ++nr)
        b[nr] = *(const bf16x8*)&Bs[wn * 32 + nr * 16 + lr][ks * 32 + lg * 8];
#pragma unroll
      for (int mr = 0; mr < 4; ++mr)
#pragma unroll
        for (int nr = 0; nr < 2; ++nr)
          acc[mr][nr] = __builtin_amdgcn_mfma_f32_16x16x32_bf16(a[mr], b[nr], acc[mr][nr], 0, 0, 0);
    }
    __syncthreads();
  }

#pragma unroll
  for (int mr = 0; mr < 4; ++mr) {
#pragma unroll
    for (int nr = 0; nr < 2; ++nr) {
      const int c = col0 + wn * 32 + nr * 16 + lr;
      const int rbase = row0 + wm * 64 + mr * 16 + lg * 4;
      if (isQ) {
        const int h = c >> 6, d = c & 63;
        const int b = rbase / 3136;
        const int n0 = rbase - b * 3136;
#pragma unroll
        for (int j = 0; j < 4; ++j)
          Qbuf[(((size_t)b * 3 + h) * 3136 + n0 + j) * 64 + d] = f2b(acc[mr][nr][j] * QSCALE);
      } else if (c < 192) {
        const int h = c >> 6, d = c & 63;
        const int b = rbase / 784;
        const int n0 = rbase - b * 784;
#pragma unroll
        for (int j = 0; j < 4; ++j)
          Kbuf[(((size_t)b * 3 + h) * 784 + n0 + j) * 64 + d] = f2b(acc[mr][nr][j]);
      } else {
        const int h = (c - 192) >> 6, d = (c - 192) & 63;
        const int b = rbase / 784;
        const int n0 = rbase - b * 784;
        uint2 v = pack4(acc[mr][nr][0], acc[mr][nr][1], acc[mr][nr][2], acc[mr][nr][3]);
        *reinterpret_cast<uint2*>(&Vtbuf[(((size_t)b * 3 + h) * 64 + d) * 784 + n0]) = v;
      }
    }
  }
}

// ---------------------------------------------------------------------------
// output projection (round-6 proven): O[25088,192](bf16) x Wo^T + bias -> fp32
// ---------------------------------------------------------------------------
__global__ __launch_bounds__(256) void gemm_out_kernel(
    const unsigned short* __restrict__ A, const unsigned short* __restrict__ Bt,
    const float* __restrict__ bias, float* __restrict__ O32)
{
  __shared__ unsigned short As[128][72];
  __shared__ unsigned short Bs[64][72];

  const int bm = blockIdx.x / 3, bn = blockIdx.x % 3;
  const int row0 = bm << 7, col0 = bn << 6;
  const int tid = threadIdx.x;
  const int lane = tid & 63, w = tid >> 6;
  const int lr = lane & 15, lg = lane >> 4;
  const int wm = w >> 1, wn = w & 1;

  f32x4 acc[4][2];
#pragma unroll
  for (int mr = 0; mr < 4; ++mr)
#pragma unroll
    for (int nr = 0; nr < 2; ++nr) acc[mr][nr] = (f32x4){0.f, 0.f, 0.f, 0.f};

  for (int k0 = 0; k0 < 192; k0 += 64) {
    {
      const int r = tid >> 1, c0 = (tid & 1) * 32;
      const unsigned short* src = A + (size_t)(row0 + r) * 192 + k0 + c0;
#pragma unroll
      for (int u = 0; u < 4; ++u)
        *(u16x8*)&As[r][c0 + u * 8] = *(const u16x8*)&src[u * 8];
    }
    {
      const int n = tid >> 2, c0 = (tid & 3) * 16;
      const unsigned short* src = Bt + (size_t)(col0 + n) * 192 + k0 + c0;
#pragma unroll
      for (int u = 0; u < 2; ++u)
        *(u16x8*)&Bs[n][c0 + u * 8] = *(const u16x8*)&src[u * 8];
    }
    __syncthreads();
#pragma unroll
    for (int ks = 0; ks < 2; ++ks) {
      bf16x8 a[4], b[2];
#pragma unroll
      for (int mr = 0; mr < 4; ++mr)
        a[mr] = *(const bf16x8*)&As[wm * 64 + mr * 16 + lr][ks * 32 + lg * 8];
#pragma unroll
      for (int nr = 0; nr < 2; ++nr)
        b[nr] = *(const bf16x8*)&Bs[wn * 32 + nr * 16 + lr][ks * 32 + lg * 8];
#pragma unroll
      for (int mr = 0; mr < 4; ++mr)
#pragma unroll
        for (int nr = 0; nr < 2; ++nr)
          acc[mr][nr] = __builtin_amdgcn_mfma_f32_16x16x32_bf16(a[mr], b[nr], acc[mr][nr], 0, 0, 0);
    }
    __syncthreads();
  }

#pragma unroll
  for (int mr = 0; mr < 4; ++mr) {
#pragma unroll
    for (int nr = 0; nr < 2; ++nr) {
      const int c = col0 + wn * 32 + nr * 16 + lr;
      const int rbase = row0 + wm * 64 + mr * 16 + lg * 4;
      const float bb = bias[c];
#pragma unroll
      for (int j = 0; j < 4; ++j)
        O32[(size_t)(rbase + j) * 192 + c] = acc[mr][nr][j] + bb;
    }
  }
}

// ---------------------------------------------------------------------------
// MFMA flash attention (round-6 proven 64-row structure) + two neutral adds:
//  - XCD-chunked block swizzle (1176 = 8*147, bijective): one bh's 49 q-tiles
//    stay on one XCD -> K/V staging reads hit that XCD's L2.
//  - s_setprio(1) around MFMA clusters (T5; helps independent-phase blocks).
// Per-row arithmetic identical to round 6 -> bitwise-identical output.
// ---------------------------------------------------------------------------
__global__ __launch_bounds__(256) void attn_mfma_kernel(
    const unsigned short* __restrict__ Qb, const unsigned short* __restrict__ Kb,
    const unsigned short* __restrict__ Vtb, unsigned short* __restrict__ Ob)
{
  __shared__ unsigned short Ks[64][72];
  __shared__ unsigned short Vts[64][72];   // V transposed tile: [d][kv_local]
  __shared__ unsigned short Ps[64][72];    // P tile (wave-private rows), 72-pad
  __shared__ float ls[4][16];

  const int raw = blockIdx.x;
  const int blk = (raw & 7) * 147 + (raw >> 3);  // XCD-chunked swizzle (8*147=1176)
  const int qt = blk % 49;
  const int bh = blk / 49;                 // b*3 + h
  const int n0 = qt * 64;
  const int tid = threadIdx.x;
  const int lane = tid & 63;
  const int w = tid >> 6;
  const int lr = lane & 15, lg = lane >> 4;
  const int srow = w * 16 + lr;            // staging row
  const int scc  = lg;                     // staging chunk

  const unsigned short* qrow = Qb + ((size_t)bh * NQ + n0 + w * 16 + lr) * 64;
  const bf16x8 aq0 = *(const bf16x8*)&qrow[lg * 8];
  const bf16x8 aq1 = *(const bf16x8*)&qrow[32 + lg * 8];

  const unsigned short* kbase = Kb + (size_t)bh * NKV * 64;
  const unsigned short* vrow  = Vtb + ((size_t)bh * 64 + srow) * NKV;

  u16x8 kr0, kr1, vr0, vr1;
  {
    const unsigned short* kp = kbase + (size_t)srow * 64;
    kr0 = *(const u16x8*)&kp[scc * 8];
    kr1 = *(const u16x8*)&kp[scc * 8 + 32];
    vr0 = *(const u16x8*)&vrow[scc * 8];
    vr1 = *(const u16x8*)&vrow[scc * 8 + 32];
  }
  *(u16x8*)&Ks[srow][scc * 8]       = kr0;
  *(u16x8*)&Ks[srow][scc * 8 + 32]  = kr1;
  *(u16x8*)&Vts[srow][scc * 8]      = vr0;
  *(u16x8*)&Vts[srow][scc * 8 + 32] = vr1;
  __syncthreads();

  f32x4 oacc[4];
#pragma unroll
  for (int db = 0; db < 4; ++db) oacc[db] = (f32x4){0.f, 0.f, 0.f, 0.f};
  float lsum = 0.f;

  for (int kt = 0; kt < 12; ++kt) {
    // prefetch tile kt+1 into regs (latency hides under compute)
    {
      const int nk = kt + 1;
      const int kvg = (nk * 64 + srow < NKV) ? nk * 64 + srow : NKV - 1;
      const unsigned short* kp = kbase + (size_t)kvg * 64;
      kr0 = *(const u16x8*)&kp[scc * 8];
      kr1 = *(const u16x8*)&kp[scc * 8 + 32];
      const int vb = nk * 64 + scc * 8;
      const int vc0 = (vb      <= NKV - 8) ? vb      : NKV - 8;
      const int vc1 = (vb + 32 <= NKV - 8) ? vb + 32 : NKV - 8;
      vr0 = *(const u16x8*)&vrow[vc0];
      vr1 = *(const u16x8*)&vrow[vc1];
    }

    // S^T = K.Q^T : st[nb][r] = S[q=lr][kv = kt*64 + nb*16 + lg*4 + r]
    f32x4 st[4];
    __builtin_amdgcn_s_setprio(1);
#pragma unroll
    for (int nb = 0; nb < 4; ++nb) {
      const bf16x8 bk0 = *(const bf16x8*)&Ks[nb * 16 + lr][lg * 8];
      const bf16x8 bk1 = *(const bf16x8*)&Ks[nb * 16 + lr][32 + lg * 8];
      f32x4 a = (f32x4){0.f, 0.f, 0.f, 0.f};
      a = __builtin_amdgcn_mfma_f32_16x16x32_bf16(bk0, aq0, a, 0, 0, 0);
      a = __builtin_amdgcn_mfma_f32_16x16x32_bf16(bk1, aq1, a, 0, 0, 0);
      st[nb] = a;
    }
    __builtin_amdgcn_s_setprio(0);

    // p = exp2(s') (log2e pre-folded into Q), partial denom, pack -> Ps
#pragma unroll
    for (int nb = 0; nb < 4; ++nb) {
      float p[4];
#pragma unroll
      for (int r = 0; r < 4; ++r) p[r] = exp2f(st[nb][r]);
      lsum += (p[0] + p[1]) + (p[2] + p[3]);
      uint2 u = pack4(p[0], p[1], p[2], p[3]);
      *reinterpret_cast<uint2*>(&Ps[w * 16 + lr][nb * 16 + lg * 4]) = u;
    }

    // O += P V  (Ps rows wave-private: same-wave DS in-order, no barrier)
    const bf16x8 pa0 = *(const bf16x8*)&Ps[w * 16 + lr][lg * 8];
    const bf16x8 pa1 = *(const bf16x8*)&Ps[w * 16 + lr][32 + lg * 8];
    __builtin_amdgcn_s_setprio(1);
#pragma unroll
    for (int db = 0; db < 4; ++db) {
      const bf16x8 vb0 = *(const bf16x8*)&Vts[db * 16 + lr][lg * 8];
      const bf16x8 vb1 = *(const bf16x8*)&Vts[db * 16 + lr][32 + lg * 8];
      oacc[db] = __builtin_amdgcn_mfma_f32_16x16x32_bf16(pa0, vb0, oacc[db], 0, 0, 0);
      oacc[db] = __builtin_amdgcn_mfma_f32_16x16x32_bf16(pa1, vb1, oacc[db], 0, 0, 0);
    }
    __builtin_amdgcn_s_setprio(0);

    // publish prefetched tile kt+1
    __syncthreads();
    *(u16x8*)&Ks[srow][scc * 8]       = kr0;
    *(u16x8*)&Ks[srow][scc * 8 + 32]  = kr1;
    *(u16x8*)&Vts[srow][scc * 8]      = vr0;
    *(u16x8*)&Vts[srow][scc * 8 + 32] = vr1;
    __syncthreads();
  }

  // tail tile (kt=12): kv 768..783 valid -> only nb=0
  {
    const bf16x8 bk0 = *(const bf16x8*)&Ks[lr][lg * 8];
    const bf16x8 bk1 = *(const bf16x8*)&Ks[lr][32 + lg * 8];
    f32x4 a = (f32x4){0.f, 0.f, 0.f, 0.f};
    a = __builtin_amdgcn_mfma_f32_16x16x32_bf16(bk0, aq0, a, 0, 0, 0);
    a = __builtin_amdgcn_mfma_f32_16x16x32_bf16(bk1, aq1, a, 0, 0, 0);
    float p[4];
#pragma unroll
    for (int r = 0; r < 4; ++r) p[r] = exp2f(a[r]);
    lsum += (p[0] + p[1]) + (p[2] + p[3]);
    *reinterpret_cast<uint2*>(&Ps[w * 16 + lr][lg * 4]) = pack4(p[0], p[1], p[2], p[3]);
    uint2 z; z.x = 0u; z.y = 0u;
    *reinterpret_cast<uint2*>(&Ps[w * 16 + lr][16 + lg * 4]) = z;
    const bf16x8 pa0 = *(const bf16x8*)&Ps[w * 16 + lr][lg * 8];
#pragma unroll
    for (int db = 0; db < 4; ++db) {
      const bf16x8 vb0 = *(const bf16x8*)&Vts[db * 16 + lr][lg * 8];
      oacc[db] = __builtin_amdgcn_mfma_f32_16x16x32_bf16(pa0, vb0, oacc[db], 0, 0, 0);
    }
  }

  float l = lsum;
  l += __shfl_xor(l, 16);
  l += __shfl_xor(l, 32);
  if (lg == 0) ls[w][lr] = l;
  const float4 lv = *(const float4*)&ls[w][lg * 4];

  const int b = bh / 3, h = bh - b * 3;
  float linv[4];
#pragma unroll
  for (int j = 0; j < 4; ++j) linv[j] = 1.f / ((&lv.x)[j]);
#pragma unroll
  for (int j = 0; j < 4; ++j) {
    const int qg = n0 + w * 16 + lg * 4 + j;
    unsigned short* orow = Ob + ((size_t)b * NQ + qg) * 192 + h * 64 + lr;
#pragma unroll
    for (int db = 0; db < 4; ++db) orow[db * 16] = f2b(oacc[db][j] * linv[j]);
  }
}

// ---------------------------------------------------------------------------
extern "C" void kernel_launch(void* const* d_in, const int* in_sizes, int n_in,
                              void* d_out, int out_size, void* d_ws, size_t ws_size,
                              hipStream_t stream)
{
  const float* x        = (const float*)d_in[0];
  const float* dw_q     = (const float*)d_in[1];
  const float* q_gamma  = (const float*)d_in[2];
  const float* q_beta   = (const float*)d_in[3];
  const float* q_mean   = (const float*)d_in[4];
  const float* q_var    = (const float*)d_in[5];
  const float* pw_q     = (const float*)d_in[6];
  const float* dw_kv    = (const float*)d_in[7];
  const float* kv_gamma = (const float*)d_in[8];
  const float* kv_beta  = (const float*)d_in[9];
  const float* kv_mean  = (const float*)d_in[10];
  const float* kv_var   = (const float*)d_in[11];
  const float* pw_kv    = (const float*)d_in[12];
  const float* out_w    = (const float*)d_in[13];
  const float* out_b    = (const float*)d_in[14];
  float* out = (float*)d_out;

  unsigned short* dwq   = (unsigned short*)d_ws;          // 25088*192 (later O)
  unsigned short* dwkv  = dwq   + (size_t)25088 * 192;    // 6272*192
  unsigned short* Qbuf  = dwkv  + (size_t)6272 * 192;     // 24*3136*64
  unsigned short* Kbuf  = Qbuf  + (size_t)24 * 3136 * 64; // 24*784*64
  unsigned short* Vtbuf = Kbuf  + (size_t)24 * 784 * 64;  // 24*64*784
  unsigned short* Wq    = Vtbuf + (size_t)24 * 784 * 64;  // 192*192
  unsigned short* Wkv   = Wq + 36864;                     // 384*192
  unsigned short* Wo    = Wkv + 73728;                    // 192*192

  // 1. fused: dwbn(q) + dwbn(kv) + weight prep
  stage1_kernel<<<6456, 256, 0, stream>>>(
      x, dw_q, q_gamma, q_beta, q_mean, q_var,
      dw_kv, kv_gamma, kv_beta, kv_mean, kv_var,
      pw_q, pw_kv, out_w, dwq, dwkv, Wq, Wkv, Wo);
  // 2. pointwise GEMMs (round-6 tiling): q -> Qbuf, kv -> Kbuf + Vtbuf
  gemm_qkv_kernel<<<882, 256, 0, stream>>>(dwq, dwkv, Wq, Wkv, Qbuf, Kbuf, Vtbuf);
  // 3. MFMA attention (64 q-rows/block, XCD swizzle + setprio) -> dwq
  attn_mfma_kernel<<<8 * 3 * 49, 256, 0, stream>>>(Qbuf, Kbuf, Vtbuf, dwq);
  // 4. output projection + bias -> d_out (fp32)
  gemm_out_kernel<<<588, 256, 0, stream>>>(dwq, Wo, out_b, out);
}